// Round 10
// baseline (511.318 us; speedup 1.0000x reference)
//
#include <hip/hip_runtime.h>
#include <math.h>

#define DD 128
#define LDSS 136            // u16 LDS row stride (128 + 8 pad)
#define PLANE (16 * LDSS)   // u16 elements per 16-row plane
#define WT 16384            // u16 elements per packed 128x128 weight matrix
#define SCAN_TILE 1024      // deg elements per scan block (256 thr x int4)

typedef __attribute__((ext_vector_type(8))) short bf16x8;
typedef __attribute__((ext_vector_type(4))) float f32x4;
typedef unsigned short u16;
typedef unsigned int u32;
struct u32x3 { u32 x, y, z; };   // 12B, align 4 -> global_load/store_dwordx3

__device__ __forceinline__ u16 f2bf(float f) {          // RNE (stored tensors)
    u32 u = __builtin_bit_cast(u32, f);
    u += 0x7fffu + ((u >> 16) & 1u);
    return (u16)(u >> 16);
}
__device__ __forceinline__ float bf2f(u16 h) {
    u32 u = ((u32)h) << 16;
    return __builtin_bit_cast(float, u);
}
__device__ __forceinline__ float mishf(float x) {
    float e = __expf(fminf(x, 15.0f));
    float n = e * (e + 2.0f);
    return x * n * __builtin_amdgcn_rcpf(n + 2.0f);
}
// truncating hi/lo split (3 VALU ops, reconstruction err ~2^-16)
__device__ __forceinline__ void splitv(float v, u16& h, u16& l) {
    u32 u = __builtin_bit_cast(u32, v);
    h = (u16)(u >> 16);
    float r = v - __builtin_bit_cast(float, u & 0xffff0000u);
    l = (u16)(__builtin_bit_cast(u32, r) >> 16);
}

__device__ __forceinline__ void zero2(f32x4* acc) {
    f32x4 z4 = {0.f, 0.f, 0.f, 0.f};
    acc[0] = z4; acc[1] = z4;
}

// prefetch the kb=0 B fragments (bh/bl for j=0,1) of a weight matrix into
// registers — issued BEFORE a __syncthreads so the L2 latency is absorbed
// in the barrier drain instead of serializing after it. 16 VGPR.
// DEPTH=1 IS THE OPTIMUM [measured]: depth-1 (round 5/8) MfmaUtil 13.0,
// 154-156us; depth-2 preB[8] (round 7) MfmaUtil 11.9, VGPR stuck at 64 —
// allocator refused to keep 32 regs live across the barrier and re-issued
// the loads after it, losing the overlap. Do not deepen again.
__device__ __forceinline__ void prefetchB4(const u16* __restrict__ Wh, const u16* __restrict__ Wl,
                                           int lane, int ntB, bf16x8* pre)
{
    size_t b0 = (((size_t)ntB + 0) * 64 + lane) * 8;   // kb=0
    size_t b1 = (((size_t)ntB + 1) * 64 + lane) * 8;
    pre[0] = *(const bf16x8*)(Wh + b0);
    pre[1] = *(const bf16x8*)(Wl + b0);
    pre[2] = *(const bf16x8*)(Wh + b1);
    pre[3] = *(const bf16x8*)(Wl + b1);
}

// 2-nt-tile GEMM slice. NM=1: ah*bh ; NM=2: ah*(bh+bl) ; NM=3: + al*bh
// SPLIT=true: kb-parity accumulator split (perf-neutral, round 4; kept).
template<int NM, bool SPLIT = false>
__device__ __forceinline__ void gemm2(const bf16x8* ah, const bf16x8* al,
    const u16* __restrict__ Wh, const u16* __restrict__ Wl, int lane, int ntB, f32x4* acc)
{
    f32x4 accB[2];
    if (SPLIT) zero2(accB);
#pragma unroll
    for (int kb = 0; kb < 4; kb++)
#pragma unroll
        for (int j = 0; j < 2; j++) {
            size_t boff = (((size_t)kb * 8 + ntB + j) * 64 + lane) * 8;
            f32x4* ac = (SPLIT && (kb & 1)) ? accB : acc;   // kb unroll-constant
            bf16x8 bh = *(const bf16x8*)(Wh + boff);
            ac[j] = __builtin_amdgcn_mfma_f32_16x16x32_bf16(ah[kb], bh, ac[j], 0, 0, 0);
            if (NM >= 2) {
                bf16x8 bl = *(const bf16x8*)(Wl + boff);
                ac[j] = __builtin_amdgcn_mfma_f32_16x16x32_bf16(ah[kb], bl, ac[j], 0, 0, 0);
            }
            if (NM == 3)
                ac[j] = __builtin_amdgcn_mfma_f32_16x16x32_bf16(al[kb], bh, ac[j], 0, 0, 0);
        }
    if (SPLIT) {
        acc[0] += accB[0];
        acc[1] += accB[1];
    }
}

// dual NM=1 pair, SHARED A: two weight streams, one A stream.
// 4 independent MFMA chains + 2x B-loads in flight vs serial gemm2<1> x2.
// (fronthist As+Bs — round-10 ILP fix, mirrors mega's gemm2_dual win)
__device__ __forceinline__ void gemm2_dual1(const bf16x8* ah,
    const u16* __restrict__ W1h, const u16* __restrict__ W2h,
    int lane, int ntB, f32x4* acc1, f32x4* acc2)
{
#pragma unroll
    for (int kb = 0; kb < 4; kb++)
#pragma unroll
        for (int j = 0; j < 2; j++) {
            size_t boff = (((size_t)kb * 8 + ntB + j) * 64 + lane) * 8;
            bf16x8 b1 = *(const bf16x8*)(W1h + boff);
            acc1[j] = __builtin_amdgcn_mfma_f32_16x16x32_bf16(ah[kb], b1, acc1[j], 0, 0, 0);
            bf16x8 b2 = *(const bf16x8*)(W2h + boff);
            acc2[j] = __builtin_amdgcn_mfma_f32_16x16x32_bf16(ah[kb], b2, acc2[j], 0, 0, 0);
        }
}

// dual NM=3 pair, SHARED A (ah, al): two hi/lo weight streams.
// Per (kb,j): 6 MFMAs / 4 loads, 4 independent chains.
__device__ __forceinline__ void gemm2_dual3(const bf16x8* ah, const bf16x8* al,
    const u16* __restrict__ W1h, const u16* __restrict__ W1l,
    const u16* __restrict__ W2h, const u16* __restrict__ W2l,
    int lane, int ntB, f32x4* acc1, f32x4* acc2)
{
#pragma unroll
    for (int kb = 0; kb < 4; kb++)
#pragma unroll
        for (int j = 0; j < 2; j++) {
            size_t boff = (((size_t)kb * 8 + ntB + j) * 64 + lane) * 8;
            bf16x8 b1h = *(const bf16x8*)(W1h + boff);
            bf16x8 b1l = *(const bf16x8*)(W1l + boff);
            acc1[j] = __builtin_amdgcn_mfma_f32_16x16x32_bf16(ah[kb], b1h, acc1[j], 0, 0, 0);
            acc1[j] = __builtin_amdgcn_mfma_f32_16x16x32_bf16(ah[kb], b1l, acc1[j], 0, 0, 0);
            acc1[j] = __builtin_amdgcn_mfma_f32_16x16x32_bf16(al[kb], b1h, acc1[j], 0, 0, 0);
            bf16x8 b2h = *(const bf16x8*)(W2h + boff);
            bf16x8 b2l = *(const bf16x8*)(W2l + boff);
            acc2[j] = __builtin_amdgcn_mfma_f32_16x16x32_bf16(ah[kb], b2h, acc2[j], 0, 0, 0);
            acc2[j] = __builtin_amdgcn_mfma_f32_16x16x32_bf16(ah[kb], b2l, acc2[j], 0, 0, 0);
            acc2[j] = __builtin_amdgcn_mfma_f32_16x16x32_bf16(al[kb], b2h, acc2[j], 0, 0, 0);
        }
}

// gemm2 with kb=0 B fragments preloaded (pre[0..3] = bh0,bl0,bh1,bl1)
template<int NM, bool SPLIT = false>
__device__ __forceinline__ void gemm2_pre(const bf16x8* ah, const bf16x8* al,
    const u16* __restrict__ Wh, const u16* __restrict__ Wl, int lane, int ntB,
    f32x4* acc, const bf16x8* pre)
{
    f32x4 accB[2];
    if (SPLIT) zero2(accB);
#pragma unroll
    for (int kb = 0; kb < 4; kb++)
#pragma unroll
        for (int j = 0; j < 2; j++) {
            size_t boff = (((size_t)kb * 8 + ntB + j) * 64 + lane) * 8;
            f32x4* ac = (SPLIT && (kb & 1)) ? accB : acc;
            bf16x8 bh = (kb == 0) ? pre[j * 2] : *(const bf16x8*)(Wh + boff);
            ac[j] = __builtin_amdgcn_mfma_f32_16x16x32_bf16(ah[kb], bh, ac[j], 0, 0, 0);
            if (NM >= 2) {
                bf16x8 bl = (kb == 0) ? pre[j * 2 + 1] : *(const bf16x8*)(Wl + boff);
                ac[j] = __builtin_amdgcn_mfma_f32_16x16x32_bf16(ah[kb], bl, ac[j], 0, 0, 0);
            }
            if (NM == 3)
                ac[j] = __builtin_amdgcn_mfma_f32_16x16x32_bf16(al[kb], bh, ac[j], 0, 0, 0);
        }
    if (SPLIT) {
        acc[0] += accB[0];
        acc[1] += accB[1];
    }
}

// dual-A NM=2 GEMM pair; stream-1 kb=0 fragments preloaded via pre.
// (stage 3 has W2==W1 so the prefetch covers both streams there.)
__device__ __forceinline__ void gemm2_dual_pre(const bf16x8* a1, const bf16x8* a2,
    const u16* __restrict__ W1h, const u16* __restrict__ W1l,
    const u16* __restrict__ W2h, const u16* __restrict__ W2l,
    int lane, int ntB, f32x4* acc1, f32x4* acc2, const bf16x8* pre)
{
#pragma unroll
    for (int kb = 0; kb < 4; kb++)
#pragma unroll
        for (int j = 0; j < 2; j++) {
            size_t boff = (((size_t)kb * 8 + ntB + j) * 64 + lane) * 8;
            bf16x8 b1h = (kb == 0) ? pre[j * 2]     : *(const bf16x8*)(W1h + boff);
            bf16x8 b1l = (kb == 0) ? pre[j * 2 + 1] : *(const bf16x8*)(W1l + boff);
            acc1[j] = __builtin_amdgcn_mfma_f32_16x16x32_bf16(a1[kb], b1h, acc1[j], 0, 0, 0);
            acc1[j] = __builtin_amdgcn_mfma_f32_16x16x32_bf16(a1[kb], b1l, acc1[j], 0, 0, 0);
            bf16x8 b2h = (W2h == W1h) ? b1h : *(const bf16x8*)(W2h + boff);
            bf16x8 b2l = (W2l == W1l) ? b1l : *(const bf16x8*)(W2l + boff);
            acc2[j] = __builtin_amdgcn_mfma_f32_16x16x32_bf16(a2[kb], b2h, acc2[j], 0, 0, 0);
            acc2[j] = __builtin_amdgcn_mfma_f32_16x16x32_bf16(a2[kb], b2l, acc2[j], 0, 0, 0);
        }
}

__device__ __forceinline__ void frag_hi_global16(const u16* __restrict__ src, int row0,
                                                 int lm, int quad, int M, bf16x8* ah)
{
    int row = row0 + lm; if (row >= M) row = M - 1;
    const u16* p = src + (size_t)row * DD + quad * 8;
#pragma unroll
    for (int kb = 0; kb < 4; kb++) ah[kb] = *(const bf16x8*)(p + kb * 32);
}
__device__ __forceinline__ void frag_split_global16(const float* __restrict__ src, int row0,
                                                    int lm, int quad, int M, bf16x8* ah, bf16x8* al)
{
    int row = row0 + lm; if (row >= M) row = M - 1;
    const float* p = src + (size_t)row * DD + quad * 8;
#pragma unroll
    for (int kb = 0; kb < 4; kb++) {
        float tmp[8];
        *(float4*)tmp       = *(const float4*)(p + kb * 32);
        *(float4*)(tmp + 4) = *(const float4*)(p + kb * 32 + 4);
#pragma unroll
        for (int j = 0; j < 8; j++) { u16 h, l; splitv(tmp[j], h, l); ah[kb][j] = (short)h; al[kb][j] = (short)l; }
    }
}
__device__ __forceinline__ void frag_hi_plane16(const u16* P, int lm, int quad, bf16x8* ah)
{
    const u16* p = P + (size_t)lm * LDSS + quad * 8;
#pragma unroll
    for (int kb = 0; kb < 4; kb++) ah[kb] = *(const bf16x8*)(p + kb * 32);
}
__device__ __forceinline__ void frag_planes16(const u16* PH, const u16* PL, int lm, int quad,
                                              bf16x8* ah, bf16x8* al)
{
    const u16* ph = PH + (size_t)lm * LDSS + quad * 8;
    const u16* pl = PL + (size_t)lm * LDSS + quad * 8;
#pragma unroll
    for (int kb = 0; kb < 4; kb++) {
        ah[kb] = *(const bf16x8*)(ph + kb * 32);
        al[kb] = *(const bf16x8*)(pl + kb * 32);
    }
}

// ============ weight prep ============
struct WSrc { const float* p[18]; };

__global__ __launch_bounds__(256) void prep_weights(WSrc ws, u16* __restrict__ Wh, u16* __restrict__ Wl)
{
    int mat = blockIdx.x >> 3, chunk = blockIdx.x & 7;
    int t = threadIdx.x;
    int tt = chunk * 4 + (t >> 6);
    int lane = t & 63;
    int kb = tt >> 3, nt = tt & 7;
    const float* __restrict__ src = ws.p[mat];
    size_t doff = (size_t)mat * WT + ((size_t)tt * 64 + lane) * 8;
    int srow = kb * 32 + ((lane >> 4) * 8);
    int scol = nt * 16 + (lane & 15);
    u16 th[8], tl[8];
#pragma unroll
    for (int j = 0; j < 8; j++) {
        float v = src[(srow + j) * DD + scol];
        u16 h = f2bf(v);
        th[j] = h;
        tl[j] = f2bf(v - bf2f(h));
    }
    *(bf16x8*)(Wh + doff) = *(bf16x8*)th;
    *(bf16x8*)(Wl + doff) = *(bf16x8*)tl;
}

// ============ front + hist packed in one launch ============
// G layout: per-lane-interleaved — row = 64 lanes x 12B triplets {As, Bs, xb}
// (u32 each); edge_agg reads one dwordx3 per edge. [round 7 win]
// ROUND 10: As+Bs dualized (gemm2_dual1) and At+Bt dualized (gemm2_dual3) —
// 4 independent MFMA chains + 2x loads in flight on the shared-A GEMMs
// (mirrors mega's gemm2_dual mechanism). xWs/Ct remain single.
__global__ __launch_bounds__(256, 4) void fronthist_kernel(
    const float* __restrict__ x, const u16* __restrict__ Wh, const u16* __restrict__ Wl,
    u16* __restrict__ G, u16* __restrict__ xWs,
    float* __restrict__ At, float* __restrict__ Bt, float* __restrict__ Ct,
    const int* __restrict__ ei, int* __restrict__ deg, int E, int M, int NBF)
{
    __shared__ u16 sP[3 * PLANE];
    const int t = threadIdx.x;
    if ((int)blockIdx.x >= NBF) {           // ---- histogram part ----
        int e = ((int)blockIdx.x - NBF) * 256 + t;
        if (e < E) atomicAdd(&deg[ei[E + e]], 1);
        return;
    }
    u16 *P0 = sP, *P1 = sP + PLANE, *P2 = sP + 2 * PLANE;
    const int wave = t >> 6, lane = t & 63;
    const int lm = lane & 15, quad = lane >> 4;
    const int ntB = wave * 2;
    const int row0 = blockIdx.x * 16;

    bf16x8 ah[4], al[4];
    {   // every wave loads the same 16 rows (L1 hits); wave 0 writes the xb plane
        int row = row0 + lm; if (row >= M) row = M - 1;
        const float* p = x + (size_t)row * DD + quad * 8;
#pragma unroll
        for (int kb = 0; kb < 4; kb++) {
            float tmp[8];
            *(float4*)tmp       = *(const float4*)(p + kb * 32);
            *(float4*)(tmp + 4) = *(const float4*)(p + kb * 32 + 4);
#pragma unroll
            for (int j = 0; j < 8; j++) {
                u16 h, l; splitv(tmp[j], h, l);
                ah[kb][j] = (short)h; al[kb][j] = (short)l;
                if (wave == 0) P0[lm * LDSS + kb * 32 + quad * 8 + j] = f2bf(tmp[j]);
            }
        }
    }
    {   // As = x@W1 -> P1  ||  Bs = x@W3 -> P2  (dual NM=1, shared A)
        f32x4 accA[2], accB[2]; zero2(accA); zero2(accB);
        gemm2_dual1(ah, Wh + 1 * WT, Wh + 3 * WT, lane, ntB, accA, accB);
#pragma unroll
        for (int r = 0; r < 4; r++)
#pragma unroll
            for (int j = 0; j < 2; j++) {
                int lidx = (quad * 4 + r) * LDSS + (ntB + j) * 16 + lm;
                P1[lidx] = f2bf(accA[j][r]);
                P2[lidx] = f2bf(accB[j][r]);
            }
    }
    __syncthreads();   // single barrier: planes complete, drain all three
#pragma unroll
    for (int i = 0; i < 4; i++) {
        int r = wave * 4 + i;
        int grow = row0 + r;
        if (grow >= M) continue;
        u16* gp = G + (size_t)grow * 384 + lane * 6;
        u32x3 v;
        v.x = *(const u32*)&P1[r * LDSS + lane * 2];   // As
        v.y = *(const u32*)&P2[r * LDSS + lane * 2];   // Bs
        v.z = *(const u32*)&P0[r * LDSS + lane * 2];   // xb
        *(u32x3*)gp = v;                               // dwordx3, 768B/wave contiguous
    }
    {   // xWs = x@W5 -> global bf16
        f32x4 acc[2]; zero2(acc);
        gemm2<1>(ah, ah, Wh + 5 * WT, Wh, lane, ntB, acc);
#pragma unroll
        for (int r = 0; r < 4; r++) {
            int grow = row0 + quad * 4 + r;
            if (grow >= M) continue;
#pragma unroll
            for (int j = 0; j < 2; j++)
                xWs[(size_t)grow * DD + (ntB + j) * 16 + lm] = f2bf(acc[j][r]);
        }
    }
    {   // At = split-x@W0  ||  Bt = split-x@W2  (dual NM=3, shared A)
        f32x4 accA[2], accB[2]; zero2(accA); zero2(accB);
        gemm2_dual3(ah, al, Wh + 0 * WT, Wl + 0 * WT, Wh + 2 * WT, Wl + 2 * WT,
                    lane, ntB, accA, accB);
#pragma unroll
        for (int r = 0; r < 4; r++) {
            int grow = row0 + quad * 4 + r;
            if (grow >= M) continue;
#pragma unroll
            for (int j = 0; j < 2; j++) {
                At[(size_t)grow * DD + (ntB + j) * 16 + lm] = accA[j][r];
                Bt[(size_t)grow * DD + (ntB + j) * 16 + lm] = accB[j][r];
            }
        }
    }
    {   // Ct = split-x@W4 (single NM=3)
        f32x4 acc[2]; zero2(acc);
        gemm2<3>(ah, al, Wh + 4 * WT, Wl + 4 * WT, lane, ntB, acc);
#pragma unroll
        for (int r = 0; r < 4; r++) {
            int grow = row0 + quad * 4 + r;
            if (grow >= M) continue;
#pragma unroll
            for (int j = 0; j < 2; j++)
                Ct[(size_t)grow * DD + (ntB + j) * 16 + lm] = acc[j][r];
        }
    }
}

// ============ CSR scan (3-phase parallel) ============
// [round 9: replaced 1-block serial scan — total 603->509us, -94us]
__global__ __launch_bounds__(256) void scan_partial(const int* __restrict__ deg,
                                                    int* __restrict__ bsum, int N)
{
    int t = threadIdx.x;
    int base = blockIdx.x * SCAN_TILE + t * 4;
    int s = 0;
    if (base + 3 < N) {
        int4 v = *(const int4*)(deg + base);
        s = v.x + v.y + v.z + v.w;
    } else {
        for (int i = 0; i < 4; i++) if (base + i < N) s += deg[base + i];
    }
    __shared__ int red[256];
    red[t] = s;
    __syncthreads();
    for (int off = 128; off > 0; off >>= 1) {
        if (t < off) red[t] += red[t + off];
        __syncthreads();
    }
    if (t == 0) bsum[blockIdx.x] = red[0];
}

__global__ __launch_bounds__(64) void scan_mid(const int* __restrict__ bsum,
                                               int* __restrict__ boff,
                                               int* __restrict__ rowptr, int nblk, int N)
{
    int l = threadIdx.x;
    int mine = (l < nblk) ? bsum[l] : 0;
    int v = mine;
    for (int off = 1; off < 64; off <<= 1) {       // inclusive wave scan (nblk <= 64)
        int u = __shfl_up(v, off);
        if (l >= off) v += u;
    }
    if (l < nblk) boff[l] = v - mine;              // exclusive
    if (l == 63) rowptr[N] = v;                    // grand total = E
}

__global__ __launch_bounds__(256) void scan_fill(const int* __restrict__ deg,
                                                 const int* __restrict__ boff,
                                                 int* __restrict__ rowptr,
                                                 int* __restrict__ cursor, int N)
{
    int t = threadIdx.x;
    int base = blockIdx.x * SCAN_TILE + t * 4;
    int d[4] = {0, 0, 0, 0};
    if (base + 3 < N) {
        int4 v = *(const int4*)(deg + base);
        d[0] = v.x; d[1] = v.y; d[2] = v.z; d[3] = v.w;
    } else {
        for (int i = 0; i < 4; i++) if (base + i < N) d[i] = deg[base + i];
    }
    int s = d[0] + d[1] + d[2] + d[3];
    __shared__ int pf[256];
    pf[t] = s;
    __syncthreads();
    for (int off = 1; off < 256; off <<= 1) {      // Hillis-Steele inclusive
        int v = pf[t];
        int u = (t >= off) ? pf[t - off] : 0;
        __syncthreads();
        pf[t] = v + u;
        __syncthreads();
    }
    int run = boff[blockIdx.x] + pf[t] - s;        // exclusive prefix for this thread
    for (int i = 0; i < 4; i++) {
        int idx = base + i;
        if (idx < N) {
            rowptr[idx] = run;
            cursor[idx] = run;
            run += d[i];
        }
    }
}

__global__ __launch_bounds__(256) void scatter_kernel(
    const int* __restrict__ ei, const int* __restrict__ bond,
    const float* __restrict__ coords, int* __restrict__ cursor,
    int2* __restrict__ csr, int E)
{
    int e = blockIdx.x * 256 + threadIdx.x;
    if (e >= E) return;
    int src = ei[e], dst = ei[E + e];
    int pos = atomicAdd(&cursor[dst], 1);
    float dx = coords[src * 3 + 0] - coords[dst * 3 + 0];
    float dy = coords[src * 3 + 1] - coords[dst * 3 + 1];
    float dz = coords[src * 3 + 2] - coords[dst * 3 + 2];
    float d2 = dx * dx + dy * dy + dz * dz;
    csr[pos] = make_int2(src | (bond[e] << 20), __float_as_int(d2));
}

// ============ per-node edge aggregation ============
// 1 wave/node (round-4's 2-wave split regressed). Interleaved-G dwordx3
// gathers (1 VMEM op/edge instead of 3) + 8-edge software pipeline —
// confirmed win round 7. Near its L3-BW floor (~614MB of G-row gathers).
__global__ __launch_bounds__(256) void edge_agg(
    const float* __restrict__ At, const float* __restrict__ Bt,
    const u16* __restrict__ G,
    const int* __restrict__ rowptr, const int2* __restrict__ csr,
    const float* __restrict__ conv_w, const float* __restrict__ conv_b,
    const float* __restrict__ b_nb, const float* __restrict__ b_el,
    u16* __restrict__ Pn, u16* __restrict__ Pe, float* __restrict__ z,
    float* __restrict__ s_arr, int N)
{
    int wave = threadIdx.x >> 6;
    int lane = threadIdx.x & 63;
    int node = blockIdx.x * 4 + wave;
    if (node >= N) return;
    int c0 = lane * 2;
    int lane6 = lane * 6;
    float2 at = *(const float2*)(At + (size_t)node * DD + c0);
    float2 bt = *(const float2*)(Bt + (size_t)node * DD + c0);
    float cb = conv_b[0];
    float cw0 = conv_w[0] + cb, cw1 = conv_w[1] + cb, cw2 = conv_w[2] + cb, cw3 = conv_w[3] + cb;
    float bn0 = b_nb[c0], bn1 = b_nb[c0 + 1];
    float be0 = b_el[c0], be1 = b_el[c0 + 1];
    float accn0 = 0.f, accn1 = 0.f, acce0 = 0.f, acce1 = 0.f, accz0 = 0.f, accz1 = 0.f, ssum = 0.f;
    int beg = rowptr[node], end = rowptr[node + 1];

    auto consume = [&](int px, float d2, u32 ga, u32 gb, u32 gx) {
        int bondv = (px >> 20) & 3;
        float w = (bondv == 0) ? cw0 : (bondv == 1) ? cw1 : (bondv == 2) ? cw2 : cw3;
        float a0 = __builtin_bit_cast(float, ga << 16), a1 = __builtin_bit_cast(float, ga & 0xffff0000u);
        float b0 = __builtin_bit_cast(float, gb << 16), b1 = __builtin_bit_cast(float, gb & 0xffff0000u);
        float x0 = __builtin_bit_cast(float, gx << 16), x1 = __builtin_bit_cast(float, gx & 0xffff0000u);
        accn0 += mishf(at.x + a0 + bn0);
        accn1 += mishf(at.y + a1 + bn1);
        acce0 += mishf(w * (bt.x + b0) + be0);
        acce1 += mishf(w * (bt.y + b1) + be1);
        accz0 += d2 * x0;
        accz1 += d2 * x1;
        ssum += d2;
    };

    int k = beg;
    for (; k + 8 <= end; k += 8) {      // 8 edges in flight, 1 dwordx3 each
        int2 pd[8];
        u32x3 g[8];
#pragma unroll
        for (int i = 0; i < 8; i++) pd[i] = csr[k + i];
#pragma unroll
        for (int i = 0; i < 8; i++)
            g[i] = *(const u32x3*)(G + (size_t)(pd[i].x & 0xFFFFF) * 384 + lane6);
#pragma unroll
        for (int i = 0; i < 8; i++)
            consume(pd[i].x, __int_as_float(pd[i].y), g[i].x, g[i].y, g[i].z);
    }
    for (; k + 4 <= end; k += 4) {
        int2 pd[4];
        u32x3 g[4];
#pragma unroll
        for (int i = 0; i < 4; i++) pd[i] = csr[k + i];
#pragma unroll
        for (int i = 0; i < 4; i++)
            g[i] = *(const u32x3*)(G + (size_t)(pd[i].x & 0xFFFFF) * 384 + lane6);
#pragma unroll
        for (int i = 0; i < 4; i++)
            consume(pd[i].x, __int_as_float(pd[i].y), g[i].x, g[i].y, g[i].z);
    }
    for (; k < end; k++) {
        int2 pd = csr[k];
        u32x3 g = *(const u32x3*)(G + (size_t)(pd.x & 0xFFFFF) * 384 + lane6);
        consume(pd.x, __int_as_float(pd.y), g.x, g.y, g.z);
    }

    *(u32*)(Pn + (size_t)node * DD + c0) = (u32)f2bf(accn0) | ((u32)f2bf(accn1) << 16);
    *(u32*)(Pe + (size_t)node * DD + c0) = (u32)f2bf(acce0) | ((u32)f2bf(acce1) << 16);
    *(float2*)(z + (size_t)node * DD + c0) = make_float2(accz0, accz1);
    if (lane == 0) s_arr[node] = ssum;
}

// ============ mega: all 3 chains + softmax + @W_agg + BN partial sums ============
// 256 threads / 16 rows, (256,3) cap=170. Round-5/8 configuration: depth-1
// B-prefetch (prefetchB4) across every barrier — measured best (154-158us,
// MfmaUtil 13.0-13.5, VGPR 60, no spill). Depth-2 regressed (round 7).
// Spill tripwire: WRITE_SIZE must stay 28125 KB.
__global__ __launch_bounds__(256, 3) void mega_kernel(
    const u16* __restrict__ Pn, const u16* __restrict__ Pe, const float* __restrict__ z,
    const float* __restrict__ Ct, const u16* __restrict__ xWs,
    const float* __restrict__ s_arr, const int* __restrict__ deg,
    const float* __restrict__ b_nout, const float* __restrict__ b_eout,
    const float* __restrict__ b_coord, const float* __restrict__ b_pair,
    const float* __restrict__ b_sout,
    const u16* __restrict__ Wh, const u16* __restrict__ Wl,
    float* __restrict__ hout, float* __restrict__ bnsums, int M)
{
    __shared__ u16 sP[4 * PLANE];
    u16 *PA = sP, *PB = sP + PLANE, *PC = sP + 2 * PLANE, *PD = sP + 3 * PLANE;
    const int t = threadIdx.x, wave = t >> 6, lane = t & 63;
    const int lm = lane & 15, quad = lane >> 4;
    const int ntB = wave * 2;
    const int row0 = blockIdx.x * 16;

    u32 f1p[4], f2p[4], f3p[4];
    float d1v[8], d2v[8];
    bf16x8 preB[4];

    // ======== node & edge chains INTERLEAVED (2 independent GEMM streams) ========
    {
        bf16x8 an[4], ae[4];
        f32x4 accn[2], acce[2];
        // stage 1: f_n, f_e
        prefetchB4(Wh + 11 * WT, Wl + 11 * WT, lane, ntB, preB);
        frag_hi_global16(Pn, row0, lm, quad, M, an);
        frag_hi_global16(Pe, row0, lm, quad, M, ae);
        zero2(accn); zero2(acce);
        gemm2_dual_pre(an, ae, Wh + 11 * WT, Wl + 11 * WT, Wh + 12 * WT, Wl + 12 * WT, lane, ntB, accn, acce, preB);
#pragma unroll
        for (int r = 0; r < 4; r++) {
            u32 pkn = 0, pke = 0;
#pragma unroll
            for (int j = 0; j < 2; j++) {
                int col = (ntB + j) * 16 + lm;
                int lidx = (quad * 4 + r) * LDSS + col;
                u16 hn = f2bf(mishf(accn[j][r] + b_nout[col]));
                u16 he = f2bf(mishf(acce[j][r] + b_eout[col]));
                pkn |= ((u32)hn) << (16 * j);
                pke |= ((u32)he) << (16 * j);
                PA[lidx] = hn; PB[lidx] = he;
            }
            f1p[r] = pkn; f2p[r] = pke;
        }
        prefetchB4(Wh + 13 * WT, Wl + 13 * WT, lane, ntB, preB);
        __syncthreads();
        // stage 2: l_n, l_e
        frag_hi_plane16(PA, lm, quad, an);
        frag_hi_plane16(PB, lm, quad, ae);
        zero2(accn); zero2(acce);
        gemm2_dual_pre(an, ae, Wh + 13 * WT, Wl + 13 * WT, Wh + 14 * WT, Wl + 14 * WT, lane, ntB, accn, acce, preB);
#pragma unroll
        for (int r = 0; r < 4; r++)
#pragma unroll
            for (int j = 0; j < 2; j++) {
                int lidx = (quad * 4 + r) * LDSS + (ntB + j) * 16 + lm;
                PC[lidx] = f2bf(mishf(mishf(accn[j][r])));
                PD[lidx] = f2bf(mishf(mishf(acce[j][r])));
            }
        prefetchB4(Wh + 16 * WT, Wl + 16 * WT, lane, ntB, preB);
        __syncthreads();
        // stage 3: d_n, d_e (shared B = Wa_b; e0 cancels in softmax)
        frag_hi_plane16(PC, lm, quad, an);
        frag_hi_plane16(PD, lm, quad, ae);
        zero2(accn); zero2(acce);
        gemm2_dual_pre(an, ae, Wh + 16 * WT, Wl + 16 * WT, Wh + 16 * WT, Wl + 16 * WT, lane, ntB, accn, acce, preB);
#pragma unroll
        for (int r = 0; r < 4; r++)
#pragma unroll
            for (int j = 0; j < 2; j++) {
                d1v[r * 2 + j] = accn[j][r];
                d2v[r * 2 + j] = acce[j][r];
            }
    }

    // ======== struct chain (hi/lo split planes) ========
    bf16x8 ah[4], al[4];
    f32x4 acc[2];
    // S1: Qagg = z@Wc_s + s*Ct + deg*b_coord -> PA/PB
    prefetchB4(Wh + 8 * WT, Wl + 8 * WT, lane, ntB, preB);
    frag_split_global16(z, row0, lm, quad, M, ah, al);
    zero2(acc);
    gemm2_pre<3, true>(ah, al, Wh + 8 * WT, Wl + 8 * WT, lane, ntB, acc, preB);
#pragma unroll
    for (int r = 0; r < 4; r++) {
        int crow = row0 + quad * 4 + r; if (crow >= M) crow = M - 1;
        float sv = s_arr[crow];
        float dv = (float)deg[crow];
#pragma unroll
        for (int j = 0; j < 2; j++) {
            int col = (ntB + j) * 16 + lm;
            float v = acc[j][r] + sv * Ct[(size_t)crow * DD + col] + dv * b_coord[col];
            int lidx = (quad * 4 + r) * LDSS + col;
            u16 h, l; splitv(v, h, l); PA[lidx] = h; PB[lidx] = l;
        }
    }
    prefetchB4(Wh + 9 * WT, Wl + 9 * WT, lane, ntB, preB);
    __syncthreads();
    // S2: Q = mish(Qagg@W_pair + b_pair) -> PC/PD
    frag_planes16(PA, PB, lm, quad, ah, al);
    zero2(acc);
    gemm2_pre<3, true>(ah, al, Wh + 9 * WT, Wl + 9 * WT, lane, ntB, acc, preB);
#pragma unroll
    for (int r = 0; r < 4; r++)
#pragma unroll
        for (int j = 0; j < 2; j++) {
            int col = (ntB + j) * 16 + lm;
            int lidx = (quad * 4 + r) * LDSS + col;
            u16 h, l; splitv(mishf(acc[j][r] + b_pair[col]), h, l); PC[lidx] = h; PD[lidx] = l;
        }
    prefetchB4(Wh + 10 * WT, Wl + 10 * WT, lane, ntB, preB);
    __syncthreads();
    // S3: f_struct = mish(Q@Ws_b + xWs + b_sout) -> f3 regs + PA/PB
    frag_planes16(PC, PD, lm, quad, ah, al);
    zero2(acc);
    gemm2_pre<3, true>(ah, al, Wh + 10 * WT, Wl + 10 * WT, lane, ntB, acc, preB);
#pragma unroll
    for (int r = 0; r < 4; r++) {
        int crow = row0 + quad * 4 + r; if (crow >= M) crow = M - 1;
        u32 pk = 0;
#pragma unroll
        for (int j = 0; j < 2; j++) {
            int col = (ntB + j) * 16 + lm;
            float v = mishf(acc[j][r] + bf2f(xWs[(size_t)crow * DD + col]) + b_sout[col]);
            u16 h, l; splitv(v, h, l);
            pk |= ((u32)f2bf(v)) << (16 * j);
            int lidx = (quad * 4 + r) * LDSS + col;
            PA[lidx] = h; PB[lidx] = l;
        }
        f3p[r] = pk;
    }
    prefetchB4(Wh + 15 * WT, Wl + 15 * WT, lane, ntB, preB);
    __syncthreads();
    // S4: l2 = mish2(f_struct@FL2) -> PC/PD
    frag_planes16(PA, PB, lm, quad, ah, al);
    zero2(acc);
    gemm2_pre<3, true>(ah, al, Wh + 15 * WT, Wl + 15 * WT, lane, ntB, acc, preB);
#pragma unroll
    for (int r = 0; r < 4; r++)
#pragma unroll
        for (int j = 0; j < 2; j++) {
            int lidx = (quad * 4 + r) * LDSS + (ntB + j) * 16 + lm;
            u16 h, l; splitv(mishf(mishf(acc[j][r])), h, l); PC[lidx] = h; PD[lidx] = l;
        }
    prefetchB4(Wh + 16 * WT, Wl + 16 * WT, lane, ntB, preB);
    __syncthreads();
    // S5: d3 = l2@Wa_b -> acc
    frag_planes16(PC, PD, lm, quad, ah, al);
    zero2(acc);
    gemm2_pre<3, true>(ah, al, Wh + 16 * WT, Wl + 16 * WT, lane, ntB, acc, preB);

    // ---- combine: softmax over paths (e0 cancels) -> att hi/lo into PA/PB ----
#pragma unroll
    for (int r = 0; r < 4; r++)
#pragma unroll
        for (int j = 0; j < 2; j++) {
            int i = r * 2 + j;
            float x1 = d1v[i], x2 = d2v[i], x3 = acc[j][r];
            float m = fmaxf(fmaxf(x1, x2), x3);
            float p1 = __expf(x1 - m), p2 = __expf(x2 - m), p3 = __expf(x3 - m);
            float fv1 = bf2f((u16)(f1p[r] >> (16 * j)));
            float fv2 = bf2f((u16)(f2p[r] >> (16 * j)));
            float fv3 = bf2f((u16)(f3p[r] >> (16 * j)));
            float att = (p1 * fv1 + p2 * fv2 + p3 * fv3) * __builtin_amdgcn_rcpf(p1 + p2 + p3);
            int lidx = (quad * 4 + r) * LDSS + (ntB + j) * 16 + lm;
            u16 h, l; splitv(att, h, l); PA[lidx] = h; PB[lidx] = l;
        }
    prefetchB4(Wh + 17 * WT, Wl + 17 * WT, lane, ntB, preB);
    __syncthreads();
    // ---- h_agg = att@W_agg -> hout fp32 + BN partial sums ----
    frag_planes16(PA, PB, lm, quad, ah, al);
    zero2(acc);
    gemm2_pre<3, true>(ah, al, Wh + 17 * WT, Wl + 17 * WT, lane, ntB, acc, preB);
    float s[2] = {0.f, 0.f}, q[2] = {0.f, 0.f};
#pragma unroll
    for (int r = 0; r < 4; r++) {
        int grow = row0 + quad * 4 + r;
        if (grow >= M) continue;
#pragma unroll
        for (int j = 0; j < 2; j++) {
            float v = acc[j][r];
            hout[(size_t)grow * DD + (ntB + j) * 16 + lm] = v;
            s[j] += v; q[j] += v * v;
        }
    }
    // per-block column reduction in LDS (planes dead), then global atomics
    __syncthreads();
    float* red = (float*)sP;                 // 256 floats
    if (t < 128) { red[t] = 0.f; red[128 + t] = 0.f; }
    __syncthreads();
#pragma unroll
    for (int j = 0; j < 2; j++) {
        int col = (ntB + j) * 16 + lm;
        atomicAdd(&red[col], s[j]);
        atomicAdd(&red[128 + col], q[j]);
    }
    __syncthreads();
    if (t < 128) {
        atomicAdd(&bnsums[t], red[t]);
        atomicAdd(&bnsums[128 + t], red[128 + t]);
    }
}

// ============ batchnorm finalize + apply ============
__global__ void bn_finalize(const float* __restrict__ sums, const float* __restrict__ gamma,
                            const float* __restrict__ beta, float* __restrict__ scale,
                            float* __restrict__ shift, float n_inv)
{
    int c = threadIdx.x;
    float mean = sums[c] * n_inv;
    float var = sums[128 + c] * n_inv - mean * mean;
    float inv = rsqrtf(var + 1e-5f);
    float sc = gamma[c] * inv;
    scale[c] = sc;
    shift[c] = beta[c] - mean * sc;
}

__global__ __launch_bounds__(256) void bn_apply(float* __restrict__ h, const float* __restrict__ scale,
                                                const float* __restrict__ shift, size_t total4)
{
    size_t idx = (size_t)blockIdx.x * 256 + threadIdx.x;
    if (idx >= total4) return;
    size_t off = idx * 4;
    int c = (int)(off & 127);
    float4 v = *(const float4*)(h + off);
    float4 sc = *(const float4*)(scale + c);
    float4 sh = *(const float4*)(shift + c);
    v.x = mishf(v.x * sc.x + sh.x);
    v.y = mishf(v.y * sc.y + sh.y);
    v.z = mishf(v.z * sc.z + sh.z);
    v.w = mishf(v.w * sc.w + sh.w);
    *(float4*)(h + off) = v;
}

// ============ host ============
extern "C" void kernel_launch(void* const* d_in, const int* in_sizes, int n_in,
                              void* d_out, int out_size, void* d_ws, size_t ws_size,
                              hipStream_t stream)
{
    (void)n_in; (void)out_size; (void)ws_size;
    const float* x       = (const float*)d_in[0];
    const float* coords  = (const float*)d_in[1];
    const int*   ei      = (const int*)d_in[2];
    const int*   bond    = (const int*)d_in[3];
    const float* W_nb    = (const float*)d_in[4];
    const float* b_nb    = (const float*)d_in[5];
    const float* W_nout  = (const float*)d_in[6];
    const float* b_nout  = (const float*)d_in[7];
    const float* conv_w  = (const float*)d_in[8];
    const float* conv_b  = (const float*)d_in[9];
    const float* W_el    = (const float*)d_in[10];
    const float* b_el    = (const float*)d_in[11];
    const float* W_eout  = (const float*)d_in[12];
    const float* b_eout  = (const float*)d_in[13];
    const float* W_coord = (const float*)d_in[14];
    const float* b_coord = (const float*)d_in[15];
    const float* W_pair  = (const float*)d_in[16];
    const float* b_pair  = (const float*)d_in[17];
    const float* W_sout  = (const float*)d_in[18];
    const float* b_sout  = (const float*)d_in[19];
    const float* W_init  = (const float*)d_in[20];
    const float* feat_lin= (const float*)d_in[21];
    const float* W_att   = (const float*)d_in[22];
    const float* W_agg   = (const float*)d_in[23];
    const float* gamma   = (const float*)d_in[24];
    const float* beta    = (const float*)d_in[25];

    const int N = in_sizes[0] / DD;     // 50000
    const int E = in_sizes[3];          // 800000
    const size_t ND = (size_t)N * DD;
    const int SUB = DD * DD;
    const int NB16 = (N + 15) / 16;
    const int EB   = (E + 255) / 256;
    const int NSCAN = (N + SCAN_TILE - 1) / SCAN_TILE;   // 49 blocks

    char* base = (char*)d_ws;
    size_t off = 0;
    auto alloc = [&](size_t bytes) -> char* {
        char* p = base + off;
        off = (off + bytes + 63) & ~(size_t)63;
        return p;
    };
    u16*   G    = (u16*)alloc((size_t)N * 384 * 2);
    u16*   xWs  = (u16*)alloc(ND * 2);
    float* At   = (float*)alloc(ND * 4);
    float* Bt   = (float*)alloc(ND * 4);
    float* Ct   = (float*)alloc(ND * 4);
    u16*   Pn   = (u16*)alloc(ND * 2);
    u16*   Pe   = (u16*)alloc(ND * 2);
    float* z    = (float*)alloc(ND * 4);
    u16*   Wh   = (u16*)alloc((size_t)18 * WT * 2);
    u16*   Wl   = (u16*)alloc((size_t)18 * WT * 2);
    int2*  csr  = (int2*)alloc((size_t)E * 8);
    int*   deg    = (int*)alloc((size_t)(N + 64) * 4);
    int*   rowptr = (int*)alloc((size_t)(N + 1) * 4);
    int*   cursor = (int*)alloc((size_t)N * 4);
    float* s_arr  = (float*)alloc((size_t)N * 4);
    int*   bsum   = (int*)alloc((size_t)(NSCAN + 64) * 4);
    int*   boff   = (int*)alloc((size_t)(NSCAN + 64) * 4);
    float* bnsums  = (float*)alloc(256 * 4);
    float* bnscale = (float*)alloc(128 * 4);
    float* bnshift = (float*)alloc(128 * 4);

    float* hout = (float*)d_out;

    WSrc wsrc;
    wsrc.p[0] = W_nb;            wsrc.p[1] = W_nb + SUB;
    wsrc.p[2] = W_el;            wsrc.p[3] = W_el + SUB;
    wsrc.p[4] = W_coord;         wsrc.p[5] = W_sout;
    wsrc.p[6] = W_init;          wsrc.p[7] = W_att;      // 6,7 unused (e0 cancels) — kept for layout
    wsrc.p[8] = W_coord + SUB;   wsrc.p[9] = W_pair;
    wsrc.p[10] = W_sout + SUB;   wsrc.p[11] = W_nout;
    wsrc.p[12] = W_eout;         wsrc.p[13] = feat_lin;
    wsrc.p[14] = feat_lin + SUB; wsrc.p[15] = feat_lin + 2 * SUB;
    wsrc.p[16] = W_att + SUB;    wsrc.p[17] = W_agg;

    const dim3 blk256(256);
    const size_t total4 = ND / 4;
    const dim3 gElem((unsigned)((total4 + 255) / 256));

    hipMemsetAsync(deg, 0, (size_t)N * 4, stream);
    hipMemsetAsync(bnsums, 0, 256 * 4, stream);

    prep_weights<<<dim3(18 * 8), blk256, 0, stream>>>(wsrc, Wh, Wl);
    fronthist_kernel<<<dim3(NB16 + EB), blk256, 0, stream>>>(x, Wh, Wl, G, xWs, At, Bt, Ct,
                                                             ei, deg, E, N, NB16);
    scan_partial<<<dim3(NSCAN), blk256, 0, stream>>>(deg, bsum, N);
    scan_mid<<<1, 64, 0, stream>>>(bsum, boff, rowptr, NSCAN, N);
    scan_fill<<<dim3(NSCAN), blk256, 0, stream>>>(deg, boff, rowptr, cursor, N);
    scatter_kernel<<<dim3(EB), blk256, 0, stream>>>(ei, bond, coords, cursor, csr, E);

    edge_agg<<<(N + 3) / 4, blk256, 0, stream>>>(At, Bt, G, rowptr, csr, conv_w, conv_b,
                                                 b_nb, b_el, Pn, Pe, z, s_arr, N);

    mega_kernel<<<NB16, blk256, 0, stream>>>(Pn, Pe, z, Ct, xWs, s_arr, deg,
                                             b_nout, b_eout, b_coord, b_pair, b_sout,
                                             Wh, Wl, hout, bnsums, N);

    bn_finalize<<<1, 128, 0, stream>>>(bnsums, gamma, beta, bnscale, bnshift, 1.0f / (float)N);
    bn_apply<<<gElem, blk256, 0, stream>>>(hout, bnscale, bnshift, total4);
}

// Round 11
// 505.018 us; speedup vs baseline: 1.0125x; 1.0125x over previous
//
#include <hip/hip_runtime.h>
#include <math.h>

#define DD 128
#define LDSS 136            // u16 LDS row stride (128 + 8 pad)
#define PLANE (16 * LDSS)   // u16 elements per 16-row plane
#define WT 16384            // u16 elements per packed 128x128 weight matrix
#define SCAN_TILE 1024      // deg elements per scan block (256 thr x int4)

typedef __attribute__((ext_vector_type(8))) short bf16x8;
typedef __attribute__((ext_vector_type(4))) float f32x4;
typedef unsigned short u16;
typedef unsigned int u32;
struct u32x3 { u32 x, y, z; };   // 12B, align 4 -> global_load/store_dwordx3

__device__ __forceinline__ u16 f2bf(float f) {          // RNE (stored tensors)
    u32 u = __builtin_bit_cast(u32, f);
    u += 0x7fffu + ((u >> 16) & 1u);
    return (u16)(u >> 16);
}
__device__ __forceinline__ float bf2f(u16 h) {
    u32 u = ((u32)h) << 16;
    return __builtin_bit_cast(float, u);
}
__device__ __forceinline__ float mishf(float x) {
    float e = __expf(fminf(x, 15.0f));
    float n = e * (e + 2.0f);
    return x * n * __builtin_amdgcn_rcpf(n + 2.0f);
}
// truncating hi/lo split (3 VALU ops, reconstruction err ~2^-16)
__device__ __forceinline__ void splitv(float v, u16& h, u16& l) {
    u32 u = __builtin_bit_cast(u32, v);
    h = (u16)(u >> 16);
    float r = v - __builtin_bit_cast(float, u & 0xffff0000u);
    l = (u16)(__builtin_bit_cast(u32, r) >> 16);
}

__device__ __forceinline__ void zero2(f32x4* acc) {
    f32x4 z4 = {0.f, 0.f, 0.f, 0.f};
    acc[0] = z4; acc[1] = z4;
}

// prefetch the kb=0 B fragments (bh/bl for j=0,1) of a weight matrix into
// registers — issued BEFORE a __syncthreads so the L2 latency is absorbed
// in the barrier drain instead of serializing after it. 16 VGPR.
// DEPTH=1 IS THE OPTIMUM [measured]: depth-1 (round 5/8) MfmaUtil 13.0;
// depth-2 preB[8] (round 7) regressed — allocator refused to keep 32 regs
// live across the barrier. Do not deepen again.
__device__ __forceinline__ void prefetchB4(const u16* __restrict__ Wh, const u16* __restrict__ Wl,
                                           int lane, int ntB, bf16x8* pre)
{
    size_t b0 = (((size_t)ntB + 0) * 64 + lane) * 8;   // kb=0
    size_t b1 = (((size_t)ntB + 1) * 64 + lane) * 8;
    pre[0] = *(const bf16x8*)(Wh + b0);
    pre[1] = *(const bf16x8*)(Wl + b0);
    pre[2] = *(const bf16x8*)(Wh + b1);
    pre[3] = *(const bf16x8*)(Wl + b1);
}

// 2-nt-tile GEMM slice. NM=1: ah*bh ; NM=2: ah*(bh+bl) ; NM=3: + al*bh
// SPLIT=true: kb-parity accumulator split (perf-neutral, round 4; kept).
template<int NM, bool SPLIT = false>
__device__ __forceinline__ void gemm2(const bf16x8* ah, const bf16x8* al,
    const u16* __restrict__ Wh, const u16* __restrict__ Wl, int lane, int ntB, f32x4* acc)
{
    f32x4 accB[2];
    if (SPLIT) zero2(accB);
#pragma unroll
    for (int kb = 0; kb < 4; kb++)
#pragma unroll
        for (int j = 0; j < 2; j++) {
            size_t boff = (((size_t)kb * 8 + ntB + j) * 64 + lane) * 8;
            f32x4* ac = (SPLIT && (kb & 1)) ? accB : acc;   // kb unroll-constant
            bf16x8 bh = *(const bf16x8*)(Wh + boff);
            ac[j] = __builtin_amdgcn_mfma_f32_16x16x32_bf16(ah[kb], bh, ac[j], 0, 0, 0);
            if (NM >= 2) {
                bf16x8 bl = *(const bf16x8*)(Wl + boff);
                ac[j] = __builtin_amdgcn_mfma_f32_16x16x32_bf16(ah[kb], bl, ac[j], 0, 0, 0);
            }
            if (NM == 3)
                ac[j] = __builtin_amdgcn_mfma_f32_16x16x32_bf16(al[kb], bh, ac[j], 0, 0, 0);
        }
    if (SPLIT) {
        acc[0] += accB[0];
        acc[1] += accB[1];
    }
}

// dual NM=1 pair, SHARED A (fronthist As+Bs; round-10, measured neutral, kept)
__device__ __forceinline__ void gemm2_dual1(const bf16x8* ah,
    const u16* __restrict__ W1h, const u16* __restrict__ W2h,
    int lane, int ntB, f32x4* acc1, f32x4* acc2)
{
#pragma unroll
    for (int kb = 0; kb < 4; kb++)
#pragma unroll
        for (int j = 0; j < 2; j++) {
            size_t boff = (((size_t)kb * 8 + ntB + j) * 64 + lane) * 8;
            bf16x8 b1 = *(const bf16x8*)(W1h + boff);
            acc1[j] = __builtin_amdgcn_mfma_f32_16x16x32_bf16(ah[kb], b1, acc1[j], 0, 0, 0);
            bf16x8 b2 = *(const bf16x8*)(W2h + boff);
            acc2[j] = __builtin_amdgcn_mfma_f32_16x16x32_bf16(ah[kb], b2, acc2[j], 0, 0, 0);
        }
}

// dual NM=3 pair, SHARED A (fronthist At+Bt; round-10, measured neutral, kept)
__device__ __forceinline__ void gemm2_dual3(const bf16x8* ah, const bf16x8* al,
    const u16* __restrict__ W1h, const u16* __restrict__ W1l,
    const u16* __restrict__ W2h, const u16* __restrict__ W2l,
    int lane, int ntB, f32x4* acc1, f32x4* acc2)
{
#pragma unroll
    for (int kb = 0; kb < 4; kb++)
#pragma unroll
        for (int j = 0; j < 2; j++) {
            size_t boff = (((size_t)kb * 8 + ntB + j) * 64 + lane) * 8;
            bf16x8 b1h = *(const bf16x8*)(W1h + boff);
            bf16x8 b1l = *(const bf16x8*)(W1l + boff);
            acc1[j] = __builtin_amdgcn_mfma_f32_16x16x32_bf16(ah[kb], b1h, acc1[j], 0, 0, 0);
            acc1[j] = __builtin_amdgcn_mfma_f32_16x16x32_bf16(ah[kb], b1l, acc1[j], 0, 0, 0);
            acc1[j] = __builtin_amdgcn_mfma_f32_16x16x32_bf16(al[kb], b1h, acc1[j], 0, 0, 0);
            bf16x8 b2h = *(const bf16x8*)(W2h + boff);
            bf16x8 b2l = *(const bf16x8*)(W2l + boff);
            acc2[j] = __builtin_amdgcn_mfma_f32_16x16x32_bf16(ah[kb], b2h, acc2[j], 0, 0, 0);
            acc2[j] = __builtin_amdgcn_mfma_f32_16x16x32_bf16(ah[kb], b2l, acc2[j], 0, 0, 0);
            acc2[j] = __builtin_amdgcn_mfma_f32_16x16x32_bf16(al[kb], b2h, acc2[j], 0, 0, 0);
        }
}

// gemm2 with kb=0 B fragments preloaded (pre[0..3] = bh0,bl0,bh1,bl1)
template<int NM, bool SPLIT = false>
__device__ __forceinline__ void gemm2_pre(const bf16x8* ah, const bf16x8* al,
    const u16* __restrict__ Wh, const u16* __restrict__ Wl, int lane, int ntB,
    f32x4* acc, const bf16x8* pre)
{
    f32x4 accB[2];
    if (SPLIT) zero2(accB);
#pragma unroll
    for (int kb = 0; kb < 4; kb++)
#pragma unroll
        for (int j = 0; j < 2; j++) {
            size_t boff = (((size_t)kb * 8 + ntB + j) * 64 + lane) * 8;
            f32x4* ac = (SPLIT && (kb & 1)) ? accB : acc;
            bf16x8 bh = (kb == 0) ? pre[j * 2] : *(const bf16x8*)(Wh + boff);
            ac[j] = __builtin_amdgcn_mfma_f32_16x16x32_bf16(ah[kb], bh, ac[j], 0, 0, 0);
            if (NM >= 2) {
                bf16x8 bl = (kb == 0) ? pre[j * 2 + 1] : *(const bf16x8*)(Wl + boff);
                ac[j] = __builtin_amdgcn_mfma_f32_16x16x32_bf16(ah[kb], bl, ac[j], 0, 0, 0);
            }
            if (NM == 3)
                ac[j] = __builtin_amdgcn_mfma_f32_16x16x32_bf16(al[kb], bh, ac[j], 0, 0, 0);
        }
    if (SPLIT) {
        acc[0] += accB[0];
        acc[1] += accB[1];
    }
}

// dual-A NM=2 GEMM pair; stream-1 kb=0 fragments preloaded via pre.
// (shared-B case W2==W1 reuses b1h/b1l registers.)
__device__ __forceinline__ void gemm2_dual_pre(const bf16x8* a1, const bf16x8* a2,
    const u16* __restrict__ W1h, const u16* __restrict__ W1l,
    const u16* __restrict__ W2h, const u16* __restrict__ W2l,
    int lane, int ntB, f32x4* acc1, f32x4* acc2, const bf16x8* pre)
{
#pragma unroll
    for (int kb = 0; kb < 4; kb++)
#pragma unroll
        for (int j = 0; j < 2; j++) {
            size_t boff = (((size_t)kb * 8 + ntB + j) * 64 + lane) * 8;
            bf16x8 b1h = (kb == 0) ? pre[j * 2]     : *(const bf16x8*)(W1h + boff);
            bf16x8 b1l = (kb == 0) ? pre[j * 2 + 1] : *(const bf16x8*)(W1l + boff);
            acc1[j] = __builtin_amdgcn_mfma_f32_16x16x32_bf16(a1[kb], b1h, acc1[j], 0, 0, 0);
            acc1[j] = __builtin_amdgcn_mfma_f32_16x16x32_bf16(a1[kb], b1l, acc1[j], 0, 0, 0);
            bf16x8 b2h = (W2h == W1h) ? b1h : *(const bf16x8*)(W2h + boff);
            bf16x8 b2l = (W2l == W1l) ? b1l : *(const bf16x8*)(W2l + boff);
            acc2[j] = __builtin_amdgcn_mfma_f32_16x16x32_bf16(a2[kb], b2h, acc2[j], 0, 0, 0);
            acc2[j] = __builtin_amdgcn_mfma_f32_16x16x32_bf16(a2[kb], b2l, acc2[j], 0, 0, 0);
        }
}

__device__ __forceinline__ void frag_hi_global16(const u16* __restrict__ src, int row0,
                                                 int lm, int quad, int M, bf16x8* ah)
{
    int row = row0 + lm; if (row >= M) row = M - 1;
    const u16* p = src + (size_t)row * DD + quad * 8;
#pragma unroll
    for (int kb = 0; kb < 4; kb++) ah[kb] = *(const bf16x8*)(p + kb * 32);
}
__device__ __forceinline__ void frag_split_global16(const float* __restrict__ src, int row0,
                                                    int lm, int quad, int M, bf16x8* ah, bf16x8* al)
{
    int row = row0 + lm; if (row >= M) row = M - 1;
    const float* p = src + (size_t)row * DD + quad * 8;
#pragma unroll
    for (int kb = 0; kb < 4; kb++) {
        float tmp[8];
        *(float4*)tmp       = *(const float4*)(p + kb * 32);
        *(float4*)(tmp + 4) = *(const float4*)(p + kb * 32 + 4);
#pragma unroll
        for (int j = 0; j < 8; j++) { u16 h, l; splitv(tmp[j], h, l); ah[kb][j] = (short)h; al[kb][j] = (short)l; }
    }
}
__device__ __forceinline__ void frag_hi_plane16(const u16* P, int lm, int quad, bf16x8* ah)
{
    const u16* p = P + (size_t)lm * LDSS + quad * 8;
#pragma unroll
    for (int kb = 0; kb < 4; kb++) ah[kb] = *(const bf16x8*)(p + kb * 32);
}
__device__ __forceinline__ void frag_planes16(const u16* PH, const u16* PL, int lm, int quad,
                                              bf16x8* ah, bf16x8* al)
{
    const u16* ph = PH + (size_t)lm * LDSS + quad * 8;
    const u16* pl = PL + (size_t)lm * LDSS + quad * 8;
#pragma unroll
    for (int kb = 0; kb < 4; kb++) {
        ah[kb] = *(const bf16x8*)(ph + kb * 32);
        al[kb] = *(const bf16x8*)(pl + kb * 32);
    }
}

// ============ weight prep ============
struct WSrc { const float* p[18]; };

__global__ __launch_bounds__(256) void prep_weights(WSrc ws, u16* __restrict__ Wh, u16* __restrict__ Wl)
{
    int mat = blockIdx.x >> 3, chunk = blockIdx.x & 7;
    int t = threadIdx.x;
    int tt = chunk * 4 + (t >> 6);
    int lane = t & 63;
    int kb = tt >> 3, nt = tt & 7;
    const float* __restrict__ src = ws.p[mat];
    size_t doff = (size_t)mat * WT + ((size_t)tt * 64 + lane) * 8;
    int srow = kb * 32 + ((lane >> 4) * 8);
    int scol = nt * 16 + (lane & 15);
    u16 th[8], tl[8];
#pragma unroll
    for (int j = 0; j < 8; j++) {
        float v = src[(srow + j) * DD + scol];
        u16 h = f2bf(v);
        th[j] = h;
        tl[j] = f2bf(v - bf2f(h));
    }
    *(bf16x8*)(Wh + doff) = *(bf16x8*)th;
    *(bf16x8*)(Wl + doff) = *(bf16x8*)tl;
}

// ============ front + hist packed in one launch ============
// G layout: per-lane-interleaved — row = 64 lanes x 12B triplets {As, Bs, xb}
// (u32 each); edge_agg reads one dwordx3 per edge. [round 7 win]
// Round-10 dualization (As+Bs, At+Bt): measured neutral, kept.
__global__ __launch_bounds__(256, 4) void fronthist_kernel(
    const float* __restrict__ x, const u16* __restrict__ Wh, const u16* __restrict__ Wl,
    u16* __restrict__ G, u16* __restrict__ xWs,
    float* __restrict__ At, float* __restrict__ Bt, float* __restrict__ Ct,
    const int* __restrict__ ei, int* __restrict__ deg, int E, int M, int NBF)
{
    __shared__ u16 sP[3 * PLANE];
    const int t = threadIdx.x;
    if ((int)blockIdx.x >= NBF) {           // ---- histogram part ----
        int e = ((int)blockIdx.x - NBF) * 256 + t;
        if (e < E) atomicAdd(&deg[ei[E + e]], 1);
        return;
    }
    u16 *P0 = sP, *P1 = sP + PLANE, *P2 = sP + 2 * PLANE;
    const int wave = t >> 6, lane = t & 63;
    const int lm = lane & 15, quad = lane >> 4;
    const int ntB = wave * 2;
    const int row0 = blockIdx.x * 16;

    bf16x8 ah[4], al[4];
    {   // every wave loads the same 16 rows (L1 hits); wave 0 writes the xb plane
        int row = row0 + lm; if (row >= M) row = M - 1;
        const float* p = x + (size_t)row * DD + quad * 8;
#pragma unroll
        for (int kb = 0; kb < 4; kb++) {
            float tmp[8];
            *(float4*)tmp       = *(const float4*)(p + kb * 32);
            *(float4*)(tmp + 4) = *(const float4*)(p + kb * 32 + 4);
#pragma unroll
            for (int j = 0; j < 8; j++) {
                u16 h, l; splitv(tmp[j], h, l);
                ah[kb][j] = (short)h; al[kb][j] = (short)l;
                if (wave == 0) P0[lm * LDSS + kb * 32 + quad * 8 + j] = f2bf(tmp[j]);
            }
        }
    }
    {   // As = x@W1 -> P1  ||  Bs = x@W3 -> P2  (dual NM=1, shared A)
        f32x4 accA[2], accB[2]; zero2(accA); zero2(accB);
        gemm2_dual1(ah, Wh + 1 * WT, Wh + 3 * WT, lane, ntB, accA, accB);
#pragma unroll
        for (int r = 0; r < 4; r++)
#pragma unroll
            for (int j = 0; j < 2; j++) {
                int lidx = (quad * 4 + r) * LDSS + (ntB + j) * 16 + lm;
                P1[lidx] = f2bf(accA[j][r]);
                P2[lidx] = f2bf(accB[j][r]);
            }
    }
    __syncthreads();   // single barrier: planes complete, drain all three
#pragma unroll
    for (int i = 0; i < 4; i++) {
        int r = wave * 4 + i;
        int grow = row0 + r;
        if (grow >= M) continue;
        u16* gp = G + (size_t)grow * 384 + lane * 6;
        u32x3 v;
        v.x = *(const u32*)&P1[r * LDSS + lane * 2];   // As
        v.y = *(const u32*)&P2[r * LDSS + lane * 2];   // Bs
        v.z = *(const u32*)&P0[r * LDSS + lane * 2];   // xb
        *(u32x3*)gp = v;                               // dwordx3, 768B/wave contiguous
    }
    {   // xWs = x@W5 -> global bf16
        f32x4 acc[2]; zero2(acc);
        gemm2<1>(ah, ah, Wh + 5 * WT, Wh, lane, ntB, acc);
#pragma unroll
        for (int r = 0; r < 4; r++) {
            int grow = row0 + quad * 4 + r;
            if (grow >= M) continue;
#pragma unroll
            for (int j = 0; j < 2; j++)
                xWs[(size_t)grow * DD + (ntB + j) * 16 + lm] = f2bf(acc[j][r]);
        }
    }
    {   // At = split-x@W0  ||  Bt = split-x@W2  (dual NM=3, shared A)
        f32x4 accA[2], accB[2]; zero2(accA); zero2(accB);
        gemm2_dual3(ah, al, Wh + 0 * WT, Wl + 0 * WT, Wh + 2 * WT, Wl + 2 * WT,
                    lane, ntB, accA, accB);
#pragma unroll
        for (int r = 0; r < 4; r++) {
            int grow = row0 + quad * 4 + r;
            if (grow >= M) continue;
#pragma unroll
            for (int j = 0; j < 2; j++) {
                At[(size_t)grow * DD + (ntB + j) * 16 + lm] = accA[j][r];
                Bt[(size_t)grow * DD + (ntB + j) * 16 + lm] = accB[j][r];
            }
        }
    }
    {   // Ct = split-x@W4 (single NM=3)
        f32x4 acc[2]; zero2(acc);
        gemm2<3>(ah, al, Wh + 4 * WT, Wl + 4 * WT, lane, ntB, acc);
#pragma unroll
        for (int r = 0; r < 4; r++) {
            int grow = row0 + quad * 4 + r;
            if (grow >= M) continue;
#pragma unroll
            for (int j = 0; j < 2; j++)
                Ct[(size_t)grow * DD + (ntB + j) * 16 + lm] = acc[j][r];
        }
    }
}

// ============ CSR scan (3-phase parallel) ============
// [round 9: replaced 1-block serial scan — total 603->509us, -94us]
__global__ __launch_bounds__(256) void scan_partial(const int* __restrict__ deg,
                                                    int* __restrict__ bsum, int N)
{
    int t = threadIdx.x;
    int base = blockIdx.x * SCAN_TILE + t * 4;
    int s = 0;
    if (base + 3 < N) {
        int4 v = *(const int4*)(deg + base);
        s = v.x + v.y + v.z + v.w;
    } else {
        for (int i = 0; i < 4; i++) if (base + i < N) s += deg[base + i];
    }
    __shared__ int red[256];
    red[t] = s;
    __syncthreads();
    for (int off = 128; off > 0; off >>= 1) {
        if (t < off) red[t] += red[t + off];
        __syncthreads();
    }
    if (t == 0) bsum[blockIdx.x] = red[0];
}

__global__ __launch_bounds__(64) void scan_mid(const int* __restrict__ bsum,
                                               int* __restrict__ boff,
                                               int* __restrict__ rowptr, int nblk, int N)
{
    int l = threadIdx.x;
    int mine = (l < nblk) ? bsum[l] : 0;
    int v = mine;
    for (int off = 1; off < 64; off <<= 1) {       // inclusive wave scan (nblk <= 64)
        int u = __shfl_up(v, off);
        if (l >= off) v += u;
    }
    if (l < nblk) boff[l] = v - mine;              // exclusive
    if (l == 63) rowptr[N] = v;                    // grand total = E
}

__global__ __launch_bounds__(256) void scan_fill(const int* __restrict__ deg,
                                                 const int* __restrict__ boff,
                                                 int* __restrict__ rowptr,
                                                 int* __restrict__ cursor, int N)
{
    int t = threadIdx.x;
    int base = blockIdx.x * SCAN_TILE + t * 4;
    int d[4] = {0, 0, 0, 0};
    if (base + 3 < N) {
        int4 v = *(const int4*)(deg + base);
        d[0] = v.x; d[1] = v.y; d[2] = v.z; d[3] = v.w;
    } else {
        for (int i = 0; i < 4; i++) if (base + i < N) d[i] = deg[base + i];
    }
    int s = d[0] + d[1] + d[2] + d[3];
    __shared__ int pf[256];
    pf[t] = s;
    __syncthreads();
    for (int off = 1; off < 256; off <<= 1) {      // Hillis-Steele inclusive
        int v = pf[t];
        int u = (t >= off) ? pf[t - off] : 0;
        __syncthreads();
        pf[t] = v + u;
        __syncthreads();
    }
    int run = boff[blockIdx.x] + pf[t] - s;        // exclusive prefix for this thread
    for (int i = 0; i < 4; i++) {
        int idx = base + i;
        if (idx < N) {
            rowptr[idx] = run;
            cursor[idx] = run;
            run += d[i];
        }
    }
}

__global__ __launch_bounds__(256) void scatter_kernel(
    const int* __restrict__ ei, const int* __restrict__ bond,
    const float* __restrict__ coords, int* __restrict__ cursor,
    int2* __restrict__ csr, int E)
{
    int e = blockIdx.x * 256 + threadIdx.x;
    if (e >= E) return;
    int src = ei[e], dst = ei[E + e];
    int pos = atomicAdd(&cursor[dst], 1);
    float dx = coords[src * 3 + 0] - coords[dst * 3 + 0];
    float dy = coords[src * 3 + 1] - coords[dst * 3 + 1];
    float dz = coords[src * 3 + 2] - coords[dst * 3 + 2];
    float d2 = dx * dx + dy * dy + dz * dz;
    csr[pos] = make_int2(src | (bond[e] << 20), __float_as_int(d2));
}

// ============ per-node edge aggregation ============
// 1 wave/node; interleaved-G dwordx3 gathers + 8-edge pipeline [round 7 win].
// Near its L3-BW floor (~614MB of fully-consumed G-row gathers).
__global__ __launch_bounds__(256) void edge_agg(
    const float* __restrict__ At, const float* __restrict__ Bt,
    const u16* __restrict__ G,
    const int* __restrict__ rowptr, const int2* __restrict__ csr,
    const float* __restrict__ conv_w, const float* __restrict__ conv_b,
    const float* __restrict__ b_nb, const float* __restrict__ b_el,
    u16* __restrict__ Pn, u16* __restrict__ Pe, float* __restrict__ z,
    float* __restrict__ s_arr, int N)
{
    int wave = threadIdx.x >> 6;
    int lane = threadIdx.x & 63;
    int node = blockIdx.x * 4 + wave;
    if (node >= N) return;
    int c0 = lane * 2;
    int lane6 = lane * 6;
    float2 at = *(const float2*)(At + (size_t)node * DD + c0);
    float2 bt = *(const float2*)(Bt + (size_t)node * DD + c0);
    float cb = conv_b[0];
    float cw0 = conv_w[0] + cb, cw1 = conv_w[1] + cb, cw2 = conv_w[2] + cb, cw3 = conv_w[3] + cb;
    float bn0 = b_nb[c0], bn1 = b_nb[c0 + 1];
    float be0 = b_el[c0], be1 = b_el[c0 + 1];
    float accn0 = 0.f, accn1 = 0.f, acce0 = 0.f, acce1 = 0.f, accz0 = 0.f, accz1 = 0.f, ssum = 0.f;
    int beg = rowptr[node], end = rowptr[node + 1];

    auto consume = [&](int px, float d2, u32 ga, u32 gb, u32 gx) {
        int bondv = (px >> 20) & 3;
        float w = (bondv == 0) ? cw0 : (bondv == 1) ? cw1 : (bondv == 2) ? cw2 : cw3;
        float a0 = __builtin_bit_cast(float, ga << 16), a1 = __builtin_bit_cast(float, ga & 0xffff0000u);
        float b0 = __builtin_bit_cast(float, gb << 16), b1 = __builtin_bit_cast(float, gb & 0xffff0000u);
        float x0 = __builtin_bit_cast(float, gx << 16), x1 = __builtin_bit_cast(float, gx & 0xffff0000u);
        accn0 += mishf(at.x + a0 + bn0);
        accn1 += mishf(at.y + a1 + bn1);
        acce0 += mishf(w * (bt.x + b0) + be0);
        acce1 += mishf(w * (bt.y + b1) + be1);
        accz0 += d2 * x0;
        accz1 += d2 * x1;
        ssum += d2;
    };

    int k = beg;
    for (; k + 8 <= end; k += 8) {      // 8 edges in flight, 1 dwordx3 each
        int2 pd[8];
        u32x3 g[8];
#pragma unroll
        for (int i = 0; i < 8; i++) pd[i] = csr[k + i];
#pragma unroll
        for (int i = 0; i < 8; i++)
            g[i] = *(const u32x3*)(G + (size_t)(pd[i].x & 0xFFFFF) * 384 + lane6);
#pragma unroll
        for (int i = 0; i < 8; i++)
            consume(pd[i].x, __int_as_float(pd[i].y), g[i].x, g[i].y, g[i].z);
    }
    for (; k + 4 <= end; k += 4) {
        int2 pd[4];
        u32x3 g[4];
#pragma unroll
        for (int i = 0; i < 4; i++) pd[i] = csr[k + i];
#pragma unroll
        for (int i = 0; i < 4; i++)
            g[i] = *(const u32x3*)(G + (size_t)(pd[i].x & 0xFFFFF) * 384 + lane6);
#pragma unroll
        for (int i = 0; i < 4; i++)
            consume(pd[i].x, __int_as_float(pd[i].y), g[i].x, g[i].y, g[i].z);
    }
    for (; k < end; k++) {
        int2 pd = csr[k];
        u32x3 g = *(const u32x3*)(G + (size_t)(pd.x & 0xFFFFF) * 384 + lane6);
        consume(pd.x, __int_as_float(pd.y), g.x, g.y, g.z);
    }

    *(u32*)(Pn + (size_t)node * DD + c0) = (u32)f2bf(accn0) | ((u32)f2bf(accn1) << 16);
    *(u32*)(Pe + (size_t)node * DD + c0) = (u32)f2bf(acce0) | ((u32)f2bf(acce1) << 16);
    *(float2*)(z + (size_t)node * DD + c0) = make_float2(accz0, accz1);
    if (lane == 0) s_arr[node] = ssum;
}

// ============ mega v3: PHASE-MERGED independent chains ============
// ROUND 11: node/edge chain (3 stages) and struct chain (6 stages) are
// independent until softmax — merge them phase-wise with 8 LDS planes:
//   A: n/e s1 (W11/W12, pre) + struct S1 (W8)      -> PA,PB | PE,PF
//   B: n/e s2 (W13/W14, pre) + struct S2 (W9)      -> PC,PD | PG,PH
//   C: n/e s3 (W16 shared, pre) + struct S3 (W10)  -> d1v,d2v | PE,PF
//   D: struct S4 (W15, pre)                        -> PG,PH
//   E: struct S5 (W16, pre) + softmax -> att       -> PA,PB
//   F: final @W_agg (W17, pre) -> hout + BN sums
// Barriers 9 -> 6; phases A-C carry ~40 MFMAs of independent work each.
// Same arithmetic, reordered only — absmax must be unchanged.
// Spill tripwire: WRITE_SIZE must stay 28125 KB.
__global__ __launch_bounds__(256, 3) void mega_kernel(
    const u16* __restrict__ Pn, const u16* __restrict__ Pe, const float* __restrict__ z,
    const float* __restrict__ Ct, const u16* __restrict__ xWs,
    const float* __restrict__ s_arr, const int* __restrict__ deg,
    const float* __restrict__ b_nout, const float* __restrict__ b_eout,
    const float* __restrict__ b_coord, const float* __restrict__ b_pair,
    const float* __restrict__ b_sout,
    const u16* __restrict__ Wh, const u16* __restrict__ Wl,
    float* __restrict__ hout, float* __restrict__ bnsums, int M)
{
    __shared__ u16 sP[8 * PLANE];
    u16 *PA = sP,             *PB = sP + PLANE,     *PC = sP + 2 * PLANE, *PD = sP + 3 * PLANE;
    u16 *PE = sP + 4 * PLANE, *PF = sP + 5 * PLANE, *PG = sP + 6 * PLANE, *PH = sP + 7 * PLANE;
    const int t = threadIdx.x, wave = t >> 6, lane = t & 63;
    const int lm = lane & 15, quad = lane >> 4;
    const int ntB = wave * 2;
    const int row0 = blockIdx.x * 16;

    u32 f1p[4], f2p[4], f3p[4];
    float d1v[8], d2v[8];
    bf16x8 preB[4];

    // ======== Phase A: n/e stage1 + struct S1 ========
    prefetchB4(Wh + 11 * WT, Wl + 11 * WT, lane, ntB, preB);
    {
        bf16x8 an[4], ae[4];
        f32x4 accn[2], acce[2];
        frag_hi_global16(Pn, row0, lm, quad, M, an);
        frag_hi_global16(Pe, row0, lm, quad, M, ae);
        zero2(accn); zero2(acce);
        gemm2_dual_pre(an, ae, Wh + 11 * WT, Wl + 11 * WT, Wh + 12 * WT, Wl + 12 * WT, lane, ntB, accn, acce, preB);
#pragma unroll
        for (int r = 0; r < 4; r++) {
            u32 pkn = 0, pke = 0;
#pragma unroll
            for (int j = 0; j < 2; j++) {
                int col = (ntB + j) * 16 + lm;
                int lidx = (quad * 4 + r) * LDSS + col;
                u16 hn = f2bf(mishf(accn[j][r] + b_nout[col]));
                u16 he = f2bf(mishf(acce[j][r] + b_eout[col]));
                pkn |= ((u32)hn) << (16 * j);
                pke |= ((u32)he) << (16 * j);
                PA[lidx] = hn; PB[lidx] = he;
            }
            f1p[r] = pkn; f2p[r] = pke;
        }
    }
    {   // struct S1: Qagg = z@W8 + s*Ct + deg*b_coord -> PE/PF
        bf16x8 ah[4], al[4];
        f32x4 acc[2];
        frag_split_global16(z, row0, lm, quad, M, ah, al);
        zero2(acc);
        gemm2<3, true>(ah, al, Wh + 8 * WT, Wl + 8 * WT, lane, ntB, acc);
#pragma unroll
        for (int r = 0; r < 4; r++) {
            int crow = row0 + quad * 4 + r; if (crow >= M) crow = M - 1;
            float sv = s_arr[crow];
            float dv = (float)deg[crow];
#pragma unroll
            for (int j = 0; j < 2; j++) {
                int col = (ntB + j) * 16 + lm;
                float v = acc[j][r] + sv * Ct[(size_t)crow * DD + col] + dv * b_coord[col];
                int lidx = (quad * 4 + r) * LDSS + col;
                u16 h, l; splitv(v, h, l); PE[lidx] = h; PF[lidx] = l;
            }
        }
    }
    prefetchB4(Wh + 13 * WT, Wl + 13 * WT, lane, ntB, preB);
    __syncthreads();

    // ======== Phase B: n/e stage2 + struct S2 ========
    {
        bf16x8 an[4], ae[4];
        f32x4 accn[2], acce[2];
        frag_hi_plane16(PA, lm, quad, an);
        frag_hi_plane16(PB, lm, quad, ae);
        zero2(accn); zero2(acce);
        gemm2_dual_pre(an, ae, Wh + 13 * WT, Wl + 13 * WT, Wh + 14 * WT, Wl + 14 * WT, lane, ntB, accn, acce, preB);
#pragma unroll
        for (int r = 0; r < 4; r++)
#pragma unroll
            for (int j = 0; j < 2; j++) {
                int lidx = (quad * 4 + r) * LDSS + (ntB + j) * 16 + lm;
                PC[lidx] = f2bf(mishf(mishf(accn[j][r])));
                PD[lidx] = f2bf(mishf(mishf(acce[j][r])));
            }
    }
    {   // struct S2: Q = mish(Qagg@W9 + b_pair) -> PG/PH
        bf16x8 ah[4], al[4];
        f32x4 acc[2];
        frag_planes16(PE, PF, lm, quad, ah, al);
        zero2(acc);
        gemm2<3, true>(ah, al, Wh + 9 * WT, Wl + 9 * WT, lane, ntB, acc);
#pragma unroll
        for (int r = 0; r < 4; r++)
#pragma unroll
            for (int j = 0; j < 2; j++) {
                int col = (ntB + j) * 16 + lm;
                int lidx = (quad * 4 + r) * LDSS + col;
                u16 h, l; splitv(mishf(acc[j][r] + b_pair[col]), h, l); PG[lidx] = h; PH[lidx] = l;
            }
    }
    prefetchB4(Wh + 16 * WT, Wl + 16 * WT, lane, ntB, preB);
    __syncthreads();

    // ======== Phase C: n/e stage3 (shared W16) + struct S3 ========
    {
        bf16x8 an[4], ae[4];
        f32x4 accn[2], acce[2];
        frag_hi_plane16(PC, lm, quad, an);
        frag_hi_plane16(PD, lm, quad, ae);
        zero2(accn); zero2(acce);
        gemm2_dual_pre(an, ae, Wh + 16 * WT, Wl + 16 * WT, Wh + 16 * WT, Wl + 16 * WT, lane, ntB, accn, acce, preB);
#pragma unroll
        for (int r = 0; r < 4; r++)
#pragma unroll
            for (int j = 0; j < 2; j++) {
                d1v[r * 2 + j] = accn[j][r];
                d2v[r * 2 + j] = acce[j][r];
            }
    }
    {   // struct S3: f_struct = mish(Q@W10 + xWs + b_sout) -> f3 regs + PE/PF
        bf16x8 ah[4], al[4];
        f32x4 acc[2];
        frag_planes16(PG, PH, lm, quad, ah, al);
        zero2(acc);
        gemm2<3, true>(ah, al, Wh + 10 * WT, Wl + 10 * WT, lane, ntB, acc);
#pragma unroll
        for (int r = 0; r < 4; r++) {
            int crow = row0 + quad * 4 + r; if (crow >= M) crow = M - 1;
            u32 pk = 0;
#pragma unroll
            for (int j = 0; j < 2; j++) {
                int col = (ntB + j) * 16 + lm;
                float v = mishf(acc[j][r] + bf2f(xWs[(size_t)crow * DD + col]) + b_sout[col]);
                u16 h, l; splitv(v, h, l);
                pk |= ((u32)f2bf(v)) << (16 * j);
                int lidx = (quad * 4 + r) * LDSS + col;
                PE[lidx] = h; PF[lidx] = l;
            }
            f3p[r] = pk;
        }
    }
    prefetchB4(Wh + 15 * WT, Wl + 15 * WT, lane, ntB, preB);
    __syncthreads();

    // ======== Phase D: struct S4 ========
    bf16x8 ah[4], al[4];
    f32x4 acc[2];
    frag_planes16(PE, PF, lm, quad, ah, al);
    zero2(acc);
    gemm2_pre<3, true>(ah, al, Wh + 15 * WT, Wl + 15 * WT, lane, ntB, acc, preB);
#pragma unroll
    for (int r = 0; r < 4; r++)
#pragma unroll
        for (int j = 0; j < 2; j++) {
            int lidx = (quad * 4 + r) * LDSS + (ntB + j) * 16 + lm;
            u16 h, l; splitv(mishf(mishf(acc[j][r])), h, l); PG[lidx] = h; PH[lidx] = l;
        }
    prefetchB4(Wh + 16 * WT, Wl + 16 * WT, lane, ntB, preB);
    __syncthreads();

    // ======== Phase E: struct S5 + softmax -> att -> PA/PB ========
    frag_planes16(PG, PH, lm, quad, ah, al);
    zero2(acc);
    gemm2_pre<3, true>(ah, al, Wh + 16 * WT, Wl + 16 * WT, lane, ntB, acc, preB);
#pragma unroll
    for (int r = 0; r < 4; r++)
#pragma unroll
        for (int j = 0; j < 2; j++) {
            int i = r * 2 + j;
            float x1 = d1v[i], x2 = d2v[i], x3 = acc[j][r];
            float m = fmaxf(fmaxf(x1, x2), x3);
            float p1 = __expf(x1 - m), p2 = __expf(x2 - m), p3 = __expf(x3 - m);
            float fv1 = bf2f((u16)(f1p[r] >> (16 * j)));
            float fv2 = bf2f((u16)(f2p[r] >> (16 * j)));
            float fv3 = bf2f((u16)(f3p[r] >> (16 * j)));
            float att = (p1 * fv1 + p2 * fv2 + p3 * fv3) * __builtin_amdgcn_rcpf(p1 + p2 + p3);
            int lidx = (quad * 4 + r) * LDSS + (ntB + j) * 16 + lm;
            u16 h, l; splitv(att, h, l); PA[lidx] = h; PB[lidx] = l;
        }
    prefetchB4(Wh + 17 * WT, Wl + 17 * WT, lane, ntB, preB);
    __syncthreads();

    // ======== Phase F: h_agg = att@W17 -> hout + BN partial sums ========
    frag_planes16(PA, PB, lm, quad, ah, al);
    zero2(acc);
    gemm2_pre<3, true>(ah, al, Wh + 17 * WT, Wl + 17 * WT, lane, ntB, acc, preB);
    float s[2] = {0.f, 0.f}, q[2] = {0.f, 0.f};
#pragma unroll
    for (int r = 0; r < 4; r++) {
        int grow = row0 + quad * 4 + r;
        if (grow >= M) continue;
#pragma unroll
        for (int j = 0; j < 2; j++) {
            float v = acc[j][r];
            hout[(size_t)grow * DD + (ntB + j) * 16 + lm] = v;
            s[j] += v; q[j] += v * v;
        }
    }
    // per-block column reduction in LDS (planes dead), then global atomics
    __syncthreads();
    float* red = (float*)sP;                 // 256 floats
    if (t < 128) { red[t] = 0.f; red[128 + t] = 0.f; }
    __syncthreads();
#pragma unroll
    for (int j = 0; j < 2; j++) {
        int col = (ntB + j) * 16 + lm;
        atomicAdd(&red[col], s[j]);
        atomicAdd(&red[128 + col], q[j]);
    }
    __syncthreads();
    if (t < 128) {
        atomicAdd(&bnsums[t], red[t]);
        atomicAdd(&bnsums[128 + t], red[128 + t]);
    }
}

// ============ batchnorm finalize + apply ============
__global__ void bn_finalize(const float* __restrict__ sums, const float* __restrict__ gamma,
                            const float* __restrict__ beta, float* __restrict__ scale,
                            float* __restrict__ shift, float n_inv)
{
    int c = threadIdx.x;
    float mean = sums[c] * n_inv;
    float var = sums[128 + c] * n_inv - mean * mean;
    float inv = rsqrtf(var + 1e-5f);
    float sc = gamma[c] * inv;
    scale[c] = sc;
    shift[c] = beta[c] - mean * sc;
}

__global__ __launch_bounds__(256) void bn_apply(float* __restrict__ h, const float* __restrict__ scale,
                                                const float* __restrict__ shift, size_t total4)
{
    size_t idx = (size_t)blockIdx.x * 256 + threadIdx.x;
    if (idx >= total4) return;
    size_t off = idx * 4;
    int c = (int)(off & 127);
    float4 v = *(const float4*)(h + off);
    float4 sc = *(const float4*)(scale + c);
    float4 sh = *(const float4*)(shift + c);
    v.x = mishf(v.x * sc.x + sh.x);
    v.y = mishf(v.y * sc.y + sh.y);
    v.z = mishf(v.z * sc.z + sh.z);
    v.w = mishf(v.w * sc.w + sh.w);
    *(float4*)(h + off) = v;
}

// ============ host ============
extern "C" void kernel_launch(void* const* d_in, const int* in_sizes, int n_in,
                              void* d_out, int out_size, void* d_ws, size_t ws_size,
                              hipStream_t stream)
{
    (void)n_in; (void)out_size; (void)ws_size;
    const float* x       = (const float*)d_in[0];
    const float* coords  = (const float*)d_in[1];
    const int*   ei      = (const int*)d_in[2];
    const int*   bond    = (const int*)d_in[3];
    const float* W_nb    = (const float*)d_in[4];
    const float* b_nb    = (const float*)d_in[5];
    const float* W_nout  = (const float*)d_in[6];
    const float* b_nout  = (const float*)d_in[7];
    const float* conv_w  = (const float*)d_in[8];
    const float* conv_b  = (const float*)d_in[9];
    const float* W_el    = (const float*)d_in[10];
    const float* b_el    = (const float*)d_in[11];
    const float* W_eout  = (const float*)d_in[12];
    const float* b_eout  = (const float*)d_in[13];
    const float* W_coord = (const float*)d_in[14];
    const float* b_coord = (const float*)d_in[15];
    const float* W_pair  = (const float*)d_in[16];
    const float* b_pair  = (const float*)d_in[17];
    const float* W_sout  = (const float*)d_in[18];
    const float* b_sout  = (const float*)d_in[19];
    const float* W_init  = (const float*)d_in[20];
    const float* feat_lin= (const float*)d_in[21];
    const float* W_att   = (const float*)d_in[22];
    const float* W_agg   = (const float*)d_in[23];
    const float* gamma   = (const float*)d_in[24];
    const float* beta    = (const float*)d_in[25];

    const int N = in_sizes[0] / DD;     // 50000
    const int E = in_sizes[3];          // 800000
    const size_t ND = (size_t)N * DD;
    const int SUB = DD * DD;
    const int NB16 = (N + 15) / 16;
    const int EB   = (E + 255) / 256;
    const int NSCAN = (N + SCAN_TILE - 1) / SCAN_TILE;   // 49 blocks

    char* base = (char*)d_ws;
    size_t off = 0;
    auto alloc = [&](size_t bytes) -> char* {
        char* p = base + off;
        off = (off + bytes + 63) & ~(size_t)63;
        return p;
    };
    u16*   G    = (u16*)alloc((size_t)N * 384 * 2);
    u16*   xWs  = (u16*)alloc(ND * 2);
    float* At   = (float*)alloc(ND * 4);
    float* Bt   = (float*)alloc(ND * 4);
    float* Ct   = (float*)alloc(ND * 4);
    u16*   Pn   = (u16*)alloc(ND * 2);
    u16*   Pe   = (u16*)alloc(ND * 2);
    float* z    = (float*)alloc(ND * 4);
    u16*   Wh   = (u16*)alloc((size_t)18 * WT * 2);
    u16*   Wl   = (u16*)alloc((size_t)18 * WT * 2);
    int2*  csr  = (int2*)alloc((size_t)E * 8);
    int*   deg    = (int*)alloc((size_t)(N + 64) * 4);
    int*   rowptr = (int*)alloc((size_t)(N + 1) * 4);
    int*   cursor = (int*)alloc((size_t)N * 4);
    float* s_arr  = (float*)alloc((size_t)N * 4);
    int*   bsum   = (int*)alloc((size_t)(NSCAN + 64) * 4);
    int*   boff   = (int*)alloc((size_t)(NSCAN + 64) * 4);
    float* bnsums  = (float*)alloc(256 * 4);
    float* bnscale = (float*)alloc(128 * 4);
    float* bnshift = (float*)alloc(128 * 4);

    float* hout = (float*)d_out;

    WSrc wsrc;
    wsrc.p[0] = W_nb;            wsrc.p[1] = W_nb + SUB;
    wsrc.p[2] = W_el;            wsrc.p[3] = W_el + SUB;
    wsrc.p[4] = W_coord;         wsrc.p[5] = W_sout;
    wsrc.p[6] = W_init;          wsrc.p[7] = W_att;      // 6,7 unused (e0 cancels) — kept for layout
    wsrc.p[8] = W_coord + SUB;   wsrc.p[9] = W_pair;
    wsrc.p[10] = W_sout + SUB;   wsrc.p[11] = W_nout;
    wsrc.p[12] = W_eout;         wsrc.p[13] = feat_lin;
    wsrc.p[14] = feat_lin + SUB; wsrc.p[15] = feat_lin + 2 * SUB;
    wsrc.p[16] = W_att + SUB;    wsrc.p[17] = W_agg;

    const dim3 blk256(256);
    const size_t total4 = ND / 4;
    const dim3 gElem((unsigned)((total4 + 255) / 256));

    hipMemsetAsync(deg, 0, (size_t)N * 4, stream);
    hipMemsetAsync(bnsums, 0, 256 * 4, stream);

    prep_weights<<<dim3(18 * 8), blk256, 0, stream>>>(wsrc, Wh, Wl);
    fronthist_kernel<<<dim3(NB16 + EB), blk256, 0, stream>>>(x, Wh, Wl, G, xWs, At, Bt, Ct,
                                                             ei, deg, E, N, NB16);
    scan_partial<<<dim3(NSCAN), blk256, 0, stream>>>(deg, bsum, N);
    scan_mid<<<1, 64, 0, stream>>>(bsum, boff, rowptr, NSCAN, N);
    scan_fill<<<dim3(NSCAN), blk256, 0, stream>>>(deg, boff, rowptr, cursor, N);
    scatter_kernel<<<dim3(EB), blk256, 0, stream>>>(ei, bond, coords, cursor, csr, E);

    edge_agg<<<(N + 3) / 4, blk256, 0, stream>>>(At, Bt, G, rowptr, csr, conv_w, conv_b,
                                                 b_nb, b_el, Pn, Pe, z, s_arr, N);

    mega_kernel<<<NB16, blk256, 0, stream>>>(Pn, Pe, z, Ct, xWs, s_arr, deg,
                                             b_nout, b_eout, b_coord, b_pair, b_sout,
                                             Wh, Wl, hout, bnsums, N);

    bn_finalize<<<1, 128, 0, stream>>>(bnsums, gamma, beta, bnscale, bnshift, 1.0f / (float)N);
    bn_apply<<<gElem, blk256, 0, stream>>>(hout, bnscale, bnshift, total4);
}

// Round 12
// 499.709 us; speedup vs baseline: 1.0232x; 1.0106x over previous
//
#include <hip/hip_runtime.h>
#include <math.h>

#define DD 128
#define LDSS 136            // u16 LDS row stride (128 + 8 pad)
#define PLANE (16 * LDSS)   // u16 elements per 16-row plane
#define WT 16384            // u16 elements per packed 128x128 weight matrix
#define SCAN_TILE 1024      // deg elements per scan block (256 thr x int4)

typedef __attribute__((ext_vector_type(8))) short bf16x8;
typedef __attribute__((ext_vector_type(4))) float f32x4;
typedef unsigned short u16;
typedef unsigned int u32;
struct u32x3 { u32 x, y, z; };   // 12B, align 4 -> global_load/store_dwordx3

__device__ __forceinline__ u16 f2bf(float f) {          // RNE (stored tensors)
    u32 u = __builtin_bit_cast(u32, f);
    u += 0x7fffu + ((u >> 16) & 1u);
    return (u16)(u >> 16);
}
__device__ __forceinline__ float bf2f(u16 h) {
    u32 u = ((u32)h) << 16;
    return __builtin_bit_cast(float, u);
}
__device__ __forceinline__ float mishf(float x) {
    float e = __expf(fminf(x, 15.0f));
    float n = e * (e + 2.0f);
    return x * n * __builtin_amdgcn_rcpf(n + 2.0f);
}
// truncating hi/lo split (3 VALU ops, reconstruction err ~2^-16)
__device__ __forceinline__ void splitv(float v, u16& h, u16& l) {
    u32 u = __builtin_bit_cast(u32, v);
    h = (u16)(u >> 16);
    float r = v - __builtin_bit_cast(float, u & 0xffff0000u);
    l = (u16)(__builtin_bit_cast(u32, r) >> 16);
}

__device__ __forceinline__ void zero2(f32x4* acc) {
    f32x4 z4 = {0.f, 0.f, 0.f, 0.f};
    acc[0] = z4; acc[1] = z4;
}

// prefetch the kb=0 B fragments (bh/bl for j=0,1) of a weight matrix into
// registers — issued BEFORE a __syncthreads so the L2 latency is absorbed
// in the barrier drain instead of serializing after it. 16 VGPR.
// DEPTH=1 IS THE OPTIMUM [measured r5/r7/r8]. Do not deepen again.
__device__ __forceinline__ void prefetchB4(const u16* __restrict__ Wh, const u16* __restrict__ Wl,
                                           int lane, int ntB, bf16x8* pre)
{
    size_t b0 = (((size_t)ntB + 0) * 64 + lane) * 8;   // kb=0
    size_t b1 = (((size_t)ntB + 1) * 64 + lane) * 8;
    pre[0] = *(const bf16x8*)(Wh + b0);
    pre[1] = *(const bf16x8*)(Wl + b0);
    pre[2] = *(const bf16x8*)(Wh + b1);
    pre[3] = *(const bf16x8*)(Wl + b1);
}

// 2-nt-tile GEMM slice. NM=1: ah*bh ; NM=2: ah*(bh+bl) ; NM=3: + al*bh
// ROUND 12: SPLIT removed from mega (was perf-neutral, r4; costs +8 unified
// regs — dropping it moves mega under the 128-reg cliff for 4 waves/SIMD).
template<int NM>
__device__ __forceinline__ void gemm2(const bf16x8* ah, const bf16x8* al,
    const u16* __restrict__ Wh, const u16* __restrict__ Wl, int lane, int ntB, f32x4* acc)
{
#pragma unroll
    for (int kb = 0; kb < 4; kb++)
#pragma unroll
        for (int j = 0; j < 2; j++) {
            size_t boff = (((size_t)kb * 8 + ntB + j) * 64 + lane) * 8;
            bf16x8 bh = *(const bf16x8*)(Wh + boff);
            acc[j] = __builtin_amdgcn_mfma_f32_16x16x32_bf16(ah[kb], bh, acc[j], 0, 0, 0);
            if (NM >= 2) {
                bf16x8 bl = *(const bf16x8*)(Wl + boff);
                acc[j] = __builtin_amdgcn_mfma_f32_16x16x32_bf16(ah[kb], bl, acc[j], 0, 0, 0);
            }
            if (NM == 3)
                acc[j] = __builtin_amdgcn_mfma_f32_16x16x32_bf16(al[kb], bh, acc[j], 0, 0, 0);
        }
}

// dual NM=1 pair, SHARED A (fronthist As+Bs; round-10, measured neutral, kept)
__device__ __forceinline__ void gemm2_dual1(const bf16x8* ah,
    const u16* __restrict__ W1h, const u16* __restrict__ W2h,
    int lane, int ntB, f32x4* acc1, f32x4* acc2)
{
#pragma unroll
    for (int kb = 0; kb < 4; kb++)
#pragma unroll
        for (int j = 0; j < 2; j++) {
            size_t boff = (((size_t)kb * 8 + ntB + j) * 64 + lane) * 8;
            bf16x8 b1 = *(const bf16x8*)(W1h + boff);
            acc1[j] = __builtin_amdgcn_mfma_f32_16x16x32_bf16(ah[kb], b1, acc1[j], 0, 0, 0);
            bf16x8 b2 = *(const bf16x8*)(W2h + boff);
            acc2[j] = __builtin_amdgcn_mfma_f32_16x16x32_bf16(ah[kb], b2, acc2[j], 0, 0, 0);
        }
}

// dual NM=3 pair, SHARED A (fronthist At+Bt; round-10, measured neutral, kept)
__device__ __forceinline__ void gemm2_dual3(const bf16x8* ah, const bf16x8* al,
    const u16* __restrict__ W1h, const u16* __restrict__ W1l,
    const u16* __restrict__ W2h, const u16* __restrict__ W2l,
    int lane, int ntB, f32x4* acc1, f32x4* acc2)
{
#pragma unroll
    for (int kb = 0; kb < 4; kb++)
#pragma unroll
        for (int j = 0; j < 2; j++) {
            size_t boff = (((size_t)kb * 8 + ntB + j) * 64 + lane) * 8;
            bf16x8 b1h = *(const bf16x8*)(W1h + boff);
            bf16x8 b1l = *(const bf16x8*)(W1l + boff);
            acc1[j] = __builtin_amdgcn_mfma_f32_16x16x32_bf16(ah[kb], b1h, acc1[j], 0, 0, 0);
            acc1[j] = __builtin_amdgcn_mfma_f32_16x16x32_bf16(ah[kb], b1l, acc1[j], 0, 0, 0);
            acc1[j] = __builtin_amdgcn_mfma_f32_16x16x32_bf16(al[kb], b1h, acc1[j], 0, 0, 0);
            bf16x8 b2h = *(const bf16x8*)(W2h + boff);
            bf16x8 b2l = *(const bf16x8*)(W2l + boff);
            acc2[j] = __builtin_amdgcn_mfma_f32_16x16x32_bf16(ah[kb], b2h, acc2[j], 0, 0, 0);
            acc2[j] = __builtin_amdgcn_mfma_f32_16x16x32_bf16(ah[kb], b2l, acc2[j], 0, 0, 0);
            acc2[j] = __builtin_amdgcn_mfma_f32_16x16x32_bf16(al[kb], b2h, acc2[j], 0, 0, 0);
        }
}

// gemm2 with kb=0 B fragments preloaded (pre[0..3] = bh0,bl0,bh1,bl1)
template<int NM>
__device__ __forceinline__ void gemm2_pre(const bf16x8* ah, const bf16x8* al,
    const u16* __restrict__ Wh, const u16* __restrict__ Wl, int lane, int ntB,
    f32x4* acc, const bf16x8* pre)
{
#pragma unroll
    for (int kb = 0; kb < 4; kb++)
#pragma unroll
        for (int j = 0; j < 2; j++) {
            size_t boff = (((size_t)kb * 8 + ntB + j) * 64 + lane) * 8;
            bf16x8 bh = (kb == 0) ? pre[j * 2] : *(const bf16x8*)(Wh + boff);
            acc[j] = __builtin_amdgcn_mfma_f32_16x16x32_bf16(ah[kb], bh, acc[j], 0, 0, 0);
            if (NM >= 2) {
                bf16x8 bl = (kb == 0) ? pre[j * 2 + 1] : *(const bf16x8*)(Wl + boff);
                acc[j] = __builtin_amdgcn_mfma_f32_16x16x32_bf16(ah[kb], bl, acc[j], 0, 0, 0);
            }
            if (NM == 3)
                acc[j] = __builtin_amdgcn_mfma_f32_16x16x32_bf16(al[kb], bh, acc[j], 0, 0, 0);
        }
}

// dual-A NM=2 GEMM pair; stream-1 kb=0 fragments preloaded via pre.
// (shared-B case W2==W1 reuses b1h/b1l registers.)
__device__ __forceinline__ void gemm2_dual_pre(const bf16x8* a1, const bf16x8* a2,
    const u16* __restrict__ W1h, const u16* __restrict__ W1l,
    const u16* __restrict__ W2h, const u16* __restrict__ W2l,
    int lane, int ntB, f32x4* acc1, f32x4* acc2, const bf16x8* pre)
{
#pragma unroll
    for (int kb = 0; kb < 4; kb++)
#pragma unroll
        for (int j = 0; j < 2; j++) {
            size_t boff = (((size_t)kb * 8 + ntB + j) * 64 + lane) * 8;
            bf16x8 b1h = (kb == 0) ? pre[j * 2]     : *(const bf16x8*)(W1h + boff);
            bf16x8 b1l = (kb == 0) ? pre[j * 2 + 1] : *(const bf16x8*)(W1l + boff);
            acc1[j] = __builtin_amdgcn_mfma_f32_16x16x32_bf16(a1[kb], b1h, acc1[j], 0, 0, 0);
            acc1[j] = __builtin_amdgcn_mfma_f32_16x16x32_bf16(a1[kb], b1l, acc1[j], 0, 0, 0);
            bf16x8 b2h = (W2h == W1h) ? b1h : *(const bf16x8*)(W2h + boff);
            bf16x8 b2l = (W2l == W1l) ? b1l : *(const bf16x8*)(W2l + boff);
            acc2[j] = __builtin_amdgcn_mfma_f32_16x16x32_bf16(a2[kb], b2h, acc2[j], 0, 0, 0);
            acc2[j] = __builtin_amdgcn_mfma_f32_16x16x32_bf16(a2[kb], b2l, acc2[j], 0, 0, 0);
        }
}

__device__ __forceinline__ void frag_hi_global16(const u16* __restrict__ src, int row0,
                                                 int lm, int quad, int M, bf16x8* ah)
{
    int row = row0 + lm; if (row >= M) row = M - 1;
    const u16* p = src + (size_t)row * DD + quad * 8;
#pragma unroll
    for (int kb = 0; kb < 4; kb++) ah[kb] = *(const bf16x8*)(p + kb * 32);
}
__device__ __forceinline__ void frag_split_global16(const float* __restrict__ src, int row0,
                                                    int lm, int quad, int M, bf16x8* ah, bf16x8* al)
{
    int row = row0 + lm; if (row >= M) row = M - 1;
    const float* p = src + (size_t)row * DD + quad * 8;
#pragma unroll
    for (int kb = 0; kb < 4; kb++) {
        float tmp[8];
        *(float4*)tmp       = *(const float4*)(p + kb * 32);
        *(float4*)(tmp + 4) = *(const float4*)(p + kb * 32 + 4);
#pragma unroll
        for (int j = 0; j < 8; j++) { u16 h, l; splitv(tmp[j], h, l); ah[kb][j] = (short)h; al[kb][j] = (short)l; }
    }
}
__device__ __forceinline__ void frag_hi_plane16(const u16* P, int lm, int quad, bf16x8* ah)
{
    const u16* p = P + (size_t)lm * LDSS + quad * 8;
#pragma unroll
    for (int kb = 0; kb < 4; kb++) ah[kb] = *(const bf16x8*)(p + kb * 32);
}
__device__ __forceinline__ void frag_planes16(const u16* PH, const u16* PL, int lm, int quad,
                                              bf16x8* ah, bf16x8* al)
{
    const u16* ph = PH + (size_t)lm * LDSS + quad * 8;
    const u16* pl = PL + (size_t)lm * LDSS + quad * 8;
#pragma unroll
    for (int kb = 0; kb < 4; kb++) {
        ah[kb] = *(const bf16x8*)(ph + kb * 32);
        al[kb] = *(const bf16x8*)(pl + kb * 32);
    }
}

// ============ weight prep ============
struct WSrc { const float* p[18]; };

__global__ __launch_bounds__(256) void prep_weights(WSrc ws, u16* __restrict__ Wh, u16* __restrict__ Wl)
{
    int mat = blockIdx.x >> 3, chunk = blockIdx.x & 7;
    int t = threadIdx.x;
    int tt = chunk * 4 + (t >> 6);
    int lane = t & 63;
    int kb = tt >> 3, nt = tt & 7;
    const float* __restrict__ src = ws.p[mat];
    size_t doff = (size_t)mat * WT + ((size_t)tt * 64 + lane) * 8;
    int srow = kb * 32 + ((lane >> 4) * 8);
    int scol = nt * 16 + (lane & 15);
    u16 th[8], tl[8];
#pragma unroll
    for (int j = 0; j < 8; j++) {
        float v = src[(srow + j) * DD + scol];
        u16 h = f2bf(v);
        th[j] = h;
        tl[j] = f2bf(v - bf2f(h));
    }
    *(bf16x8*)(Wh + doff) = *(bf16x8*)th;
    *(bf16x8*)(Wl + doff) = *(bf16x8*)tl;
}

// ============ front + hist packed in one launch ============
// G layout: per-lane-interleaved — row = 64 lanes x 12B triplets {As, Bs, xb}
// (u32 each); edge_agg reads one dwordx3 per edge. [round 7 win]
// Round-10 dualization (As+Bs, At+Bt): measured neutral, kept.
__global__ __launch_bounds__(256, 4) void fronthist_kernel(
    const float* __restrict__ x, const u16* __restrict__ Wh, const u16* __restrict__ Wl,
    u16* __restrict__ G, u16* __restrict__ xWs,
    float* __restrict__ At, float* __restrict__ Bt, float* __restrict__ Ct,
    const int* __restrict__ ei, int* __restrict__ deg, int E, int M, int NBF)
{
    __shared__ u16 sP[3 * PLANE];
    const int t = threadIdx.x;
    if ((int)blockIdx.x >= NBF) {           // ---- histogram part ----
        int e = ((int)blockIdx.x - NBF) * 256 + t;
        if (e < E) atomicAdd(&deg[ei[E + e]], 1);
        return;
    }
    u16 *P0 = sP, *P1 = sP + PLANE, *P2 = sP + 2 * PLANE;
    const int wave = t >> 6, lane = t & 63;
    const int lm = lane & 15, quad = lane >> 4;
    const int ntB = wave * 2;
    const int row0 = blockIdx.x * 16;

    bf16x8 ah[4], al[4];
    {   // every wave loads the same 16 rows (L1 hits); wave 0 writes the xb plane
        int row = row0 + lm; if (row >= M) row = M - 1;
        const float* p = x + (size_t)row * DD + quad * 8;
#pragma unroll
        for (int kb = 0; kb < 4; kb++) {
            float tmp[8];
            *(float4*)tmp       = *(const float4*)(p + kb * 32);
            *(float4*)(tmp + 4) = *(const float4*)(p + kb * 32 + 4);
#pragma unroll
            for (int j = 0; j < 8; j++) {
                u16 h, l; splitv(tmp[j], h, l);
                ah[kb][j] = (short)h; al[kb][j] = (short)l;
                if (wave == 0) P0[lm * LDSS + kb * 32 + quad * 8 + j] = f2bf(tmp[j]);
            }
        }
    }
    {   // As = x@W1 -> P1  ||  Bs = x@W3 -> P2  (dual NM=1, shared A)
        f32x4 accA[2], accB[2]; zero2(accA); zero2(accB);
        gemm2_dual1(ah, Wh + 1 * WT, Wh + 3 * WT, lane, ntB, accA, accB);
#pragma unroll
        for (int r = 0; r < 4; r++)
#pragma unroll
            for (int j = 0; j < 2; j++) {
                int lidx = (quad * 4 + r) * LDSS + (ntB + j) * 16 + lm;
                P1[lidx] = f2bf(accA[j][r]);
                P2[lidx] = f2bf(accB[j][r]);
            }
    }
    __syncthreads();   // single barrier: planes complete, drain all three
#pragma unroll
    for (int i = 0; i < 4; i++) {
        int r = wave * 4 + i;
        int grow = row0 + r;
        if (grow >= M) continue;
        u16* gp = G + (size_t)grow * 384 + lane * 6;
        u32x3 v;
        v.x = *(const u32*)&P1[r * LDSS + lane * 2];   // As
        v.y = *(const u32*)&P2[r * LDSS + lane * 2];   // Bs
        v.z = *(const u32*)&P0[r * LDSS + lane * 2];   // xb
        *(u32x3*)gp = v;                               // dwordx3, 768B/wave contiguous
    }
    {   // xWs = x@W5 -> global bf16
        f32x4 acc[2]; zero2(acc);
        gemm2<1>(ah, ah, Wh + 5 * WT, Wh, lane, ntB, acc);
#pragma unroll
        for (int r = 0; r < 4; r++) {
            int grow = row0 + quad * 4 + r;
            if (grow >= M) continue;
#pragma unroll
            for (int j = 0; j < 2; j++)
                xWs[(size_t)grow * DD + (ntB + j) * 16 + lm] = f2bf(acc[j][r]);
        }
    }
    {   // At = split-x@W0  ||  Bt = split-x@W2  (dual NM=3, shared A)
        f32x4 accA[2], accB[2]; zero2(accA); zero2(accB);
        gemm2_dual3(ah, al, Wh + 0 * WT, Wl + 0 * WT, Wh + 2 * WT, Wl + 2 * WT,
                    lane, ntB, accA, accB);
#pragma unroll
        for (int r = 0; r < 4; r++) {
            int grow = row0 + quad * 4 + r;
            if (grow >= M) continue;
#pragma unroll
            for (int j = 0; j < 2; j++) {
                At[(size_t)grow * DD + (ntB + j) * 16 + lm] = accA[j][r];
                Bt[(size_t)grow * DD + (ntB + j) * 16 + lm] = accB[j][r];
            }
        }
    }
    {   // Ct = split-x@W4 (single NM=3)
        f32x4 acc[2]; zero2(acc);
        gemm2<3>(ah, al, Wh + 4 * WT, Wl + 4 * WT, lane, ntB, acc);
#pragma unroll
        for (int r = 0; r < 4; r++) {
            int grow = row0 + quad * 4 + r;
            if (grow >= M) continue;
#pragma unroll
            for (int j = 0; j < 2; j++)
                Ct[(size_t)grow * DD + (ntB + j) * 16 + lm] = acc[j][r];
        }
    }
}

// ============ CSR scan (3-phase parallel) ============
// [round 9: replaced 1-block serial scan — total 603->509us, -94us]
__global__ __launch_bounds__(256) void scan_partial(const int* __restrict__ deg,
                                                    int* __restrict__ bsum, int N)
{
    int t = threadIdx.x;
    int base = blockIdx.x * SCAN_TILE + t * 4;
    int s = 0;
    if (base + 3 < N) {
        int4 v = *(const int4*)(deg + base);
        s = v.x + v.y + v.z + v.w;
    } else {
        for (int i = 0; i < 4; i++) if (base + i < N) s += deg[base + i];
    }
    __shared__ int red[256];
    red[t] = s;
    __syncthreads();
    for (int off = 128; off > 0; off >>= 1) {
        if (t < off) red[t] += red[t + off];
        __syncthreads();
    }
    if (t == 0) bsum[blockIdx.x] = red[0];
}

__global__ __launch_bounds__(64) void scan_mid(const int* __restrict__ bsum,
                                               int* __restrict__ boff,
                                               int* __restrict__ rowptr, int nblk, int N)
{
    int l = threadIdx.x;
    int mine = (l < nblk) ? bsum[l] : 0;
    int v = mine;
    for (int off = 1; off < 64; off <<= 1) {       // inclusive wave scan (nblk <= 64)
        int u = __shfl_up(v, off);
        if (l >= off) v += u;
    }
    if (l < nblk) boff[l] = v - mine;              // exclusive
    if (l == 63) rowptr[N] = v;                    // grand total = E
}

__global__ __launch_bounds__(256) void scan_fill(const int* __restrict__ deg,
                                                 const int* __restrict__ boff,
                                                 int* __restrict__ rowptr,
                                                 int* __restrict__ cursor, int N)
{
    int t = threadIdx.x;
    int base = blockIdx.x * SCAN_TILE + t * 4;
    int d[4] = {0, 0, 0, 0};
    if (base + 3 < N) {
        int4 v = *(const int4*)(deg + base);
        d[0] = v.x; d[1] = v.y; d[2] = v.z; d[3] = v.w;
    } else {
        for (int i = 0; i < 4; i++) if (base + i < N) d[i] = deg[base + i];
    }
    int s = d[0] + d[1] + d[2] + d[3];
    __shared__ int pf[256];
    pf[t] = s;
    __syncthreads();
    for (int off = 1; off < 256; off <<= 1) {      // Hillis-Steele inclusive
        int v = pf[t];
        int u = (t >= off) ? pf[t - off] : 0;
        __syncthreads();
        pf[t] = v + u;
        __syncthreads();
    }
    int run = boff[blockIdx.x] + pf[t] - s;        // exclusive prefix for this thread
    for (int i = 0; i < 4; i++) {
        int idx = base + i;
        if (idx < N) {
            rowptr[idx] = run;
            cursor[idx] = run;
            run += d[i];
        }
    }
}

__global__ __launch_bounds__(256) void scatter_kernel(
    const int* __restrict__ ei, const int* __restrict__ bond,
    const float* __restrict__ coords, int* __restrict__ cursor,
    int2* __restrict__ csr, int E)
{
    int e = blockIdx.x * 256 + threadIdx.x;
    if (e >= E) return;
    int src = ei[e], dst = ei[E + e];
    int pos = atomicAdd(&cursor[dst], 1);
    float dx = coords[src * 3 + 0] - coords[dst * 3 + 0];
    float dy = coords[src * 3 + 1] - coords[dst * 3 + 1];
    float dz = coords[src * 3 + 2] - coords[dst * 3 + 2];
    float d2 = dx * dx + dy * dy + dz * dz;
    csr[pos] = make_int2(src | (bond[e] << 20), __float_as_int(d2));
}

// ============ per-node edge aggregation ============
// 1 wave/node; interleaved-G dwordx3 gathers + 8-edge pipeline [round 7 win].
// Near its L3-BW floor (~614MB of fully-consumed G-row gathers).
__global__ __launch_bounds__(256) void edge_agg(
    const float* __restrict__ At, const float* __restrict__ Bt,
    const u16* __restrict__ G,
    const int* __restrict__ rowptr, const int2* __restrict__ csr,
    const float* __restrict__ conv_w, const float* __restrict__ conv_b,
    const float* __restrict__ b_nb, const float* __restrict__ b_el,
    u16* __restrict__ Pn, u16* __restrict__ Pe, float* __restrict__ z,
    float* __restrict__ s_arr, int N)
{
    int wave = threadIdx.x >> 6;
    int lane = threadIdx.x & 63;
    int node = blockIdx.x * 4 + wave;
    if (node >= N) return;
    int c0 = lane * 2;
    int lane6 = lane * 6;
    float2 at = *(const float2*)(At + (size_t)node * DD + c0);
    float2 bt = *(const float2*)(Bt + (size_t)node * DD + c0);
    float cb = conv_b[0];
    float cw0 = conv_w[0] + cb, cw1 = conv_w[1] + cb, cw2 = conv_w[2] + cb, cw3 = conv_w[3] + cb;
    float bn0 = b_nb[c0], bn1 = b_nb[c0 + 1];
    float be0 = b_el[c0], be1 = b_el[c0 + 1];
    float accn0 = 0.f, accn1 = 0.f, acce0 = 0.f, acce1 = 0.f, accz0 = 0.f, accz1 = 0.f, ssum = 0.f;
    int beg = rowptr[node], end = rowptr[node + 1];

    auto consume = [&](int px, float d2, u32 ga, u32 gb, u32 gx) {
        int bondv = (px >> 20) & 3;
        float w = (bondv == 0) ? cw0 : (bondv == 1) ? cw1 : (bondv == 2) ? cw2 : cw3;
        float a0 = __builtin_bit_cast(float, ga << 16), a1 = __builtin_bit_cast(float, ga & 0xffff0000u);
        float b0 = __builtin_bit_cast(float, gb << 16), b1 = __builtin_bit_cast(float, gb & 0xffff0000u);
        float x0 = __builtin_bit_cast(float, gx << 16), x1 = __builtin_bit_cast(float, gx & 0xffff0000u);
        accn0 += mishf(at.x + a0 + bn0);
        accn1 += mishf(at.y + a1 + bn1);
        acce0 += mishf(w * (bt.x + b0) + be0);
        acce1 += mishf(w * (bt.y + b1) + be1);
        accz0 += d2 * x0;
        accz1 += d2 * x1;
        ssum += d2;
    };

    int k = beg;
    for (; k + 8 <= end; k += 8) {      // 8 edges in flight, 1 dwordx3 each
        int2 pd[8];
        u32x3 g[8];
#pragma unroll
        for (int i = 0; i < 8; i++) pd[i] = csr[k + i];
#pragma unroll
        for (int i = 0; i < 8; i++)
            g[i] = *(const u32x3*)(G + (size_t)(pd[i].x & 0xFFFFF) * 384 + lane6);
#pragma unroll
        for (int i = 0; i < 8; i++)
            consume(pd[i].x, __int_as_float(pd[i].y), g[i].x, g[i].y, g[i].z);
    }
    for (; k + 4 <= end; k += 4) {
        int2 pd[4];
        u32x3 g[4];
#pragma unroll
        for (int i = 0; i < 4; i++) pd[i] = csr[k + i];
#pragma unroll
        for (int i = 0; i < 4; i++)
            g[i] = *(const u32x3*)(G + (size_t)(pd[i].x & 0xFFFFF) * 384 + lane6);
#pragma unroll
        for (int i = 0; i < 4; i++)
            consume(pd[i].x, __int_as_float(pd[i].y), g[i].x, g[i].y, g[i].z);
    }
    for (; k < end; k++) {
        int2 pd = csr[k];
        u32x3 g = *(const u32x3*)(G + (size_t)(pd.x & 0xFFFFF) * 384 + lane6);
        consume(pd.x, __int_as_float(pd.y), g.x, g.y, g.z);
    }

    *(u32*)(Pn + (size_t)node * DD + c0) = (u32)f2bf(accn0) | ((u32)f2bf(accn1) << 16);
    *(u32*)(Pe + (size_t)node * DD + c0) = (u32)f2bf(acce0) | ((u32)f2bf(acce1) << 16);
    *(float2*)(z + (size_t)node * DD + c0) = make_float2(accz0, accz1);
    if (lane == 0) s_arr[node] = ssum;
}

// ============ mega v4: phase-merged + 4-waves/SIMD register budget ============
// ROUND 12: __launch_bounds__(256,4) (cap 128 unified) + SPLIT accumulators
// removed (-8 regs, perf-neutral per r4) — targets the 128-reg cliff where
// the VGPR pool admits 4 waves/SIMD (16 waves/CU) instead of 3.
// Phase plan (r11, kept): A: n/e s1 + S1 ; B: n/e s2 + S2 ; C: n/e s3 + S3 ;
// D: S4 ; E: S5 + softmax ; F: @W_agg + BN. 6 barriers.
// Spill tripwire: WRITE_SIZE must stay 28125 KB — if it jumps, REVERT to
// r11's (256,3)+SPLIT.
__global__ __launch_bounds__(256, 4) void mega_kernel(
    const u16* __restrict__ Pn, const u16* __restrict__ Pe, const float* __restrict__ z,
    const float* __restrict__ Ct, const u16* __restrict__ xWs,
    const float* __restrict__ s_arr, const int* __restrict__ deg,
    const float* __restrict__ b_nout, const float* __restrict__ b_eout,
    const float* __restrict__ b_coord, const float* __restrict__ b_pair,
    const float* __restrict__ b_sout,
    const u16* __restrict__ Wh, const u16* __restrict__ Wl,
    float* __restrict__ hout, float* __restrict__ bnsums, int M)
{
    __shared__ u16 sP[8 * PLANE];
    u16 *PA = sP,             *PB = sP + PLANE,     *PC = sP + 2 * PLANE, *PD = sP + 3 * PLANE;
    u16 *PE = sP + 4 * PLANE, *PF = sP + 5 * PLANE, *PG = sP + 6 * PLANE, *PH = sP + 7 * PLANE;
    const int t = threadIdx.x, wave = t >> 6, lane = t & 63;
    const int lm = lane & 15, quad = lane >> 4;
    const int ntB = wave * 2;
    const int row0 = blockIdx.x * 16;

    u32 f1p[4], f2p[4], f3p[4];
    float d1v[8], d2v[8];
    bf16x8 preB[4];

    // ======== Phase A: n/e stage1 + struct S1 ========
    prefetchB4(Wh + 11 * WT, Wl + 11 * WT, lane, ntB, preB);
    {
        bf16x8 an[4], ae[4];
        f32x4 accn[2], acce[2];
        frag_hi_global16(Pn, row0, lm, quad, M, an);
        frag_hi_global16(Pe, row0, lm, quad, M, ae);
        zero2(accn); zero2(acce);
        gemm2_dual_pre(an, ae, Wh + 11 * WT, Wl + 11 * WT, Wh + 12 * WT, Wl + 12 * WT, lane, ntB, accn, acce, preB);
#pragma unroll
        for (int r = 0; r < 4; r++) {
            u32 pkn = 0, pke = 0;
#pragma unroll
            for (int j = 0; j < 2; j++) {
                int col = (ntB + j) * 16 + lm;
                int lidx = (quad * 4 + r) * LDSS + col;
                u16 hn = f2bf(mishf(accn[j][r] + b_nout[col]));
                u16 he = f2bf(mishf(acce[j][r] + b_eout[col]));
                pkn |= ((u32)hn) << (16 * j);
                pke |= ((u32)he) << (16 * j);
                PA[lidx] = hn; PB[lidx] = he;
            }
            f1p[r] = pkn; f2p[r] = pke;
        }
    }
    {   // struct S1: Qagg = z@W8 + s*Ct + deg*b_coord -> PE/PF
        bf16x8 ah[4], al[4];
        f32x4 acc[2];
        frag_split_global16(z, row0, lm, quad, M, ah, al);
        zero2(acc);
        gemm2<3>(ah, al, Wh + 8 * WT, Wl + 8 * WT, lane, ntB, acc);
#pragma unroll
        for (int r = 0; r < 4; r++) {
            int crow = row0 + quad * 4 + r; if (crow >= M) crow = M - 1;
            float sv = s_arr[crow];
            float dv = (float)deg[crow];
#pragma unroll
            for (int j = 0; j < 2; j++) {
                int col = (ntB + j) * 16 + lm;
                float v = acc[j][r] + sv * Ct[(size_t)crow * DD + col] + dv * b_coord[col];
                int lidx = (quad * 4 + r) * LDSS + col;
                u16 h, l; splitv(v, h, l); PE[lidx] = h; PF[lidx] = l;
            }
        }
    }
    prefetchB4(Wh + 13 * WT, Wl + 13 * WT, lane, ntB, preB);
    __syncthreads();

    // ======== Phase B: n/e stage2 + struct S2 ========
    {
        bf16x8 an[4], ae[4];
        f32x4 accn[2], acce[2];
        frag_hi_plane16(PA, lm, quad, an);
        frag_hi_plane16(PB, lm, quad, ae);
        zero2(accn); zero2(acce);
        gemm2_dual_pre(an, ae, Wh + 13 * WT, Wl + 13 * WT, Wh + 14 * WT, Wl + 14 * WT, lane, ntB, accn, acce, preB);
#pragma unroll
        for (int r = 0; r < 4; r++)
#pragma unroll
            for (int j = 0; j < 2; j++) {
                int lidx = (quad * 4 + r) * LDSS + (ntB + j) * 16 + lm;
                PC[lidx] = f2bf(mishf(mishf(accn[j][r])));
                PD[lidx] = f2bf(mishf(mishf(acce[j][r])));
            }
    }
    {   // struct S2: Q = mish(Qagg@W9 + b_pair) -> PG/PH
        bf16x8 ah[4], al[4];
        f32x4 acc[2];
        frag_planes16(PE, PF, lm, quad, ah, al);
        zero2(acc);
        gemm2<3>(ah, al, Wh + 9 * WT, Wl + 9 * WT, lane, ntB, acc);
#pragma unroll
        for (int r = 0; r < 4; r++)
#pragma unroll
            for (int j = 0; j < 2; j++) {
                int col = (ntB + j) * 16 + lm;
                int lidx = (quad * 4 + r) * LDSS + col;
                u16 h, l; splitv(mishf(acc[j][r] + b_pair[col]), h, l); PG[lidx] = h; PH[lidx] = l;
            }
    }
    prefetchB4(Wh + 16 * WT, Wl + 16 * WT, lane, ntB, preB);
    __syncthreads();

    // ======== Phase C: n/e stage3 (shared W16) + struct S3 ========
    {
        bf16x8 an[4], ae[4];
        f32x4 accn[2], acce[2];
        frag_hi_plane16(PC, lm, quad, an);
        frag_hi_plane16(PD, lm, quad, ae);
        zero2(accn); zero2(acce);
        gemm2_dual_pre(an, ae, Wh + 16 * WT, Wl + 16 * WT, Wh + 16 * WT, Wl + 16 * WT, lane, ntB, accn, acce, preB);
#pragma unroll
        for (int r = 0; r < 4; r++)
#pragma unroll
            for (int j = 0; j < 2; j++) {
                d1v[r * 2 + j] = accn[j][r];
                d2v[r * 2 + j] = acce[j][r];
            }
    }
    {   // struct S3: f_struct = mish(Q@W10 + xWs + b_sout) -> f3 regs + PE/PF
        bf16x8 ah[4], al[4];
        f32x4 acc[2];
        frag_planes16(PG, PH, lm, quad, ah, al);
        zero2(acc);
        gemm2<3>(ah, al, Wh + 10 * WT, Wl + 10 * WT, lane, ntB, acc);
#pragma unroll
        for (int r = 0; r < 4; r++) {
            int crow = row0 + quad * 4 + r; if (crow >= M) crow = M - 1;
            u32 pk = 0;
#pragma unroll
            for (int j = 0; j < 2; j++) {
                int col = (ntB + j) * 16 + lm;
                float v = mishf(acc[j][r] + bf2f(xWs[(size_t)crow * DD + col]) + b_sout[col]);
                u16 h, l; splitv(v, h, l);
                pk |= ((u32)f2bf(v)) << (16 * j);
                int lidx = (quad * 4 + r) * LDSS + col;
                PE[lidx] = h; PF[lidx] = l;
            }
            f3p[r] = pk;
        }
    }
    prefetchB4(Wh + 15 * WT, Wl + 15 * WT, lane, ntB, preB);
    __syncthreads();

    // ======== Phase D: struct S4 ========
    bf16x8 ah[4], al[4];
    f32x4 acc[2];
    frag_planes16(PE, PF, lm, quad, ah, al);
    zero2(acc);
    gemm2_pre<3>(ah, al, Wh + 15 * WT, Wl + 15 * WT, lane, ntB, acc, preB);
#pragma unroll
    for (int r = 0; r < 4; r++)
#pragma unroll
        for (int j = 0; j < 2; j++) {
            int lidx = (quad * 4 + r) * LDSS + (ntB + j) * 16 + lm;
            u16 h, l; splitv(mishf(mishf(acc[j][r])), h, l); PG[lidx] = h; PH[lidx] = l;
        }
    prefetchB4(Wh + 16 * WT, Wl + 16 * WT, lane, ntB, preB);
    __syncthreads();

    // ======== Phase E: struct S5 + softmax -> att -> PA/PB ========
    frag_planes16(PG, PH, lm, quad, ah, al);
    zero2(acc);
    gemm2_pre<3>(ah, al, Wh + 16 * WT, Wl + 16 * WT, lane, ntB, acc, preB);
#pragma unroll
    for (int r = 0; r < 4; r++)
#pragma unroll
        for (int j = 0; j < 2; j++) {
            int i = r * 2 + j;
            float x1 = d1v[i], x2 = d2v[i], x3 = acc[j][r];
            float m = fmaxf(fmaxf(x1, x2), x3);
            float p1 = __expf(x1 - m), p2 = __expf(x2 - m), p3 = __expf(x3 - m);
            float fv1 = bf2f((u16)(f1p[r] >> (16 * j)));
            float fv2 = bf2f((u16)(f2p[r] >> (16 * j)));
            float fv3 = bf2f((u16)(f3p[r] >> (16 * j)));
            float att = (p1 * fv1 + p2 * fv2 + p3 * fv3) * __builtin_amdgcn_rcpf(p1 + p2 + p3);
            int lidx = (quad * 4 + r) * LDSS + (ntB + j) * 16 + lm;
            u16 h, l; splitv(att, h, l); PA[lidx] = h; PB[lidx] = l;
        }
    prefetchB4(Wh + 17 * WT, Wl + 17 * WT, lane, ntB, preB);
    __syncthreads();

    // ======== Phase F: h_agg = att@W17 -> hout + BN partial sums ========
    frag_planes16(PA, PB, lm, quad, ah, al);
    zero2(acc);
    gemm2_pre<3>(ah, al, Wh + 17 * WT, Wl + 17 * WT, lane, ntB, acc, preB);
    float s[2] = {0.f, 0.f}, q[2] = {0.f, 0.f};
#pragma unroll
    for (int r = 0; r < 4; r++) {
        int grow = row0 + quad * 4 + r;
        if (grow >= M) continue;
#pragma unroll
        for (int j = 0; j < 2; j++) {
            float v = acc[j][r];
            hout[(size_t)grow * DD + (ntB + j) * 16 + lm] = v;
            s[j] += v; q[j] += v * v;
        }
    }
    // per-block column reduction in LDS (planes dead), then global atomics
    __syncthreads();
    float* red = (float*)sP;                 // 256 floats
    if (t < 128) { red[t] = 0.f; red[128 + t] = 0.f; }
    __syncthreads();
#pragma unroll
    for (int j = 0; j < 2; j++) {
        int col = (ntB + j) * 16 + lm;
        atomicAdd(&red[col], s[j]);
        atomicAdd(&red[128 + col], q[j]);
    }
    __syncthreads();
    if (t < 128) {
        atomicAdd(&bnsums[t], red[t]);
        atomicAdd(&bnsums[128 + t], red[128 + t]);
    }
}

// ============ batchnorm finalize + apply ============
__global__ void bn_finalize(const float* __restrict__ sums, const float* __restrict__ gamma,
                            const float* __restrict__ beta, float* __restrict__ scale,
                            float* __restrict__ shift, float n_inv)
{
    int c = threadIdx.x;
    float mean = sums[c] * n_inv;
    float var = sums[128 + c] * n_inv - mean * mean;
    float inv = rsqrtf(var + 1e-5f);
    float sc = gamma[c] * inv;
    scale[c] = sc;
    shift[c] = beta[c] - mean * sc;
}

__global__ __launch_bounds__(256) void bn_apply(float* __restrict__ h, const float* __restrict__ scale,
                                                const float* __restrict__ shift, size_t total4)
{
    size_t idx = (size_t)blockIdx.x * 256 + threadIdx.x;
    if (idx >= total4) return;
    size_t off = idx * 4;
    int c = (int)(off & 127);
    float4 v = *(const float4*)(h + off);
    float4 sc = *(const float4*)(scale + c);
    float4 sh = *(const float4*)(shift + c);
    v.x = mishf(v.x * sc.x + sh.x);
    v.y = mishf(v.y * sc.y + sh.y);
    v.z = mishf(v.z * sc.z + sh.z);
    v.w = mishf(v.w * sc.w + sh.w);
    *(float4*)(h + off) = v;
}

// ============ host ============
extern "C" void kernel_launch(void* const* d_in, const int* in_sizes, int n_in,
                              void* d_out, int out_size, void* d_ws, size_t ws_size,
                              hipStream_t stream)
{
    (void)n_in; (void)out_size; (void)ws_size;
    const float* x       = (const float*)d_in[0];
    const float* coords  = (const float*)d_in[1];
    const int*   ei      = (const int*)d_in[2];
    const int*   bond    = (const int*)d_in[3];
    const float* W_nb    = (const float*)d_in[4];
    const float* b_nb    = (const float*)d_in[5];
    const float* W_nout  = (const float*)d_in[6];
    const float* b_nout  = (const float*)d_in[7];
    const float* conv_w  = (const float*)d_in[8];
    const float* conv_b  = (const float*)d_in[9];
    const float* W_el    = (const float*)d_in[10];
    const float* b_el    = (const float*)d_in[11];
    const float* W_eout  = (const float*)d_in[12];
    const float* b_eout  = (const float*)d_in[13];
    const float* W_coord = (const float*)d_in[14];
    const float* b_coord = (const float*)d_in[15];
    const float* W_pair  = (const float*)d_in[16];
    const float* b_pair  = (const float*)d_in[17];
    const float* W_sout  = (const float*)d_in[18];
    const float* b_sout  = (const float*)d_in[19];
    const float* W_init  = (const float*)d_in[20];
    const float* feat_lin= (const float*)d_in[21];
    const float* W_att   = (const float*)d_in[22];
    const float* W_agg   = (const float*)d_in[23];
    const float* gamma   = (const float*)d_in[24];
    const float* beta    = (const float*)d_in[25];

    const int N = in_sizes[0] / DD;     // 50000
    const int E = in_sizes[3];          // 800000
    const size_t ND = (size_t)N * DD;
    const int SUB = DD * DD;
    const int NB16 = (N + 15) / 16;
    const int EB   = (E + 255) / 256;
    const int NSCAN = (N + SCAN_TILE - 1) / SCAN_TILE;   // 49 blocks

    char* base = (char*)d_ws;
    size_t off = 0;
    auto alloc = [&](size_t bytes) -> char* {
        char* p = base + off;
        off = (off + bytes + 63) & ~(size_t)63;
        return p;
    };
    u16*   G    = (u16*)alloc((size_t)N * 384 * 2);
    u16*   xWs  = (u16*)alloc(ND * 2);
    float* At   = (float*)alloc(ND * 4);
    float* Bt   = (float*)alloc(ND * 4);
    float* Ct   = (float*)alloc(ND * 4);
    u16*   Pn   = (u16*)alloc(ND * 2);
    u16*   Pe   = (u16*)alloc(ND * 2);
    float* z    = (float*)alloc(ND * 4);
    u16*   Wh   = (u16*)alloc((size_t)18 * WT * 2);
    u16*   Wl   = (u16*)alloc((size_t)18 * WT * 2);
    int2*  csr  = (int2*)alloc((size_t)E * 8);
    int*   deg    = (int*)alloc((size_t)(N + 64) * 4);
    int*   rowptr = (int*)alloc((size_t)(N + 1) * 4);
    int*   cursor = (int*)alloc((size_t)N * 4);
    float* s_arr  = (float*)alloc((size_t)N * 4);
    int*   bsum   = (int*)alloc((size_t)(NSCAN + 64) * 4);
    int*   boff   = (int*)alloc((size_t)(NSCAN + 64) * 4);
    float* bnsums  = (float*)alloc(256 * 4);
    float* bnscale = (float*)alloc(128 * 4);
    float* bnshift = (float*)alloc(128 * 4);

    float* hout = (float*)d_out;

    WSrc wsrc;
    wsrc.p[0] = W_nb;            wsrc.p[1] = W_nb + SUB;
    wsrc.p[2] = W_el;            wsrc.p[3] = W_el + SUB;
    wsrc.p[4] = W_coord;         wsrc.p[5] = W_sout;
    wsrc.p[6] = W_init;          wsrc.p[7] = W_att;      // 6,7 unused (e0 cancels) — kept for layout
    wsrc.p[8] = W_coord + SUB;   wsrc.p[9] = W_pair;
    wsrc.p[10] = W_sout + SUB;   wsrc.p[11] = W_nout;
    wsrc.p[12] = W_eout;         wsrc.p[13] = feat_lin;
    wsrc.p[14] = feat_lin + SUB; wsrc.p[15] = feat_lin + 2 * SUB;
    wsrc.p[16] = W_att + SUB;    wsrc.p[17] = W_agg;

    const dim3 blk256(256);
    const size_t total4 = ND / 4;
    const dim3 gElem((unsigned)((total4 + 255) / 256));

    hipMemsetAsync(deg, 0, (size_t)N * 4, stream);
    hipMemsetAsync(bnsums, 0, 256 * 4, stream);

    prep_weights<<<dim3(18 * 8), blk256, 0, stream>>>(wsrc, Wh, Wl);
    fronthist_kernel<<<dim3(NB16 + EB), blk256, 0, stream>>>(x, Wh, Wl, G, xWs, At, Bt, Ct,
                                                             ei, deg, E, N, NB16);
    scan_partial<<<dim3(NSCAN), blk256, 0, stream>>>(deg, bsum, N);
    scan_mid<<<1, 64, 0, stream>>>(bsum, boff, rowptr, NSCAN, N);
    scan_fill<<<dim3(NSCAN), blk256, 0, stream>>>(deg, boff, rowptr, cursor, N);
    scatter_kernel<<<dim3(EB), blk256, 0, stream>>>(ei, bond, coords, cursor, csr, E);

    edge_agg<<<(N + 3) / 4, blk256, 0, stream>>>(At, Bt, G, rowptr, csr, conv_w, conv_b,
                                                 b_nb, b_el, Pn, Pe, z, s_arr, N);

    mega_kernel<<<NB16, blk256, 0, stream>>>(Pn, Pe, z, Ct, xWs, s_arr, deg,
                                             b_nout, b_eout, b_coord, b_pair, b_sout,
                                             Wh, Wl, hout, bnsums, N);

    bn_finalize<<<1, 128, 0, stream>>>(bnsums, gamma, beta, bnscale, bnshift, 1.0f / (float)N);
    bn_apply<<<gElem, blk256, 0, stream>>>(hout, bnscale, bnshift, total4);
}

// Round 13
// 498.553 us; speedup vs baseline: 1.0256x; 1.0023x over previous
//
#include <hip/hip_runtime.h>
#include <math.h>

#define DD 128
#define LDSS 136            // u16 LDS row stride (128 + 8 pad)
#define PLANE (16 * LDSS)   // u16 elements per 16-row plane
#define WT 16384            // u16 elements per packed 128x128 weight matrix
#define SCAN_TILE 1024      // deg elements per scan block (256 thr x int4)

typedef __attribute__((ext_vector_type(8))) short bf16x8;
typedef __attribute__((ext_vector_type(4))) float f32x4;
typedef unsigned short u16;
typedef unsigned int u32;
struct u32x3 { u32 x, y, z; };   // 12B, align 4 -> global_load/store_dwordx3

__device__ __forceinline__ u16 f2bf(float f) {          // RNE (stored tensors)
    u32 u = __builtin_bit_cast(u32, f);
    u += 0x7fffu + ((u >> 16) & 1u);
    return (u16)(u >> 16);
}
__device__ __forceinline__ float bf2f(u16 h) {
    u32 u = ((u32)h) << 16;
    return __builtin_bit_cast(float, u);
}
__device__ __forceinline__ float mishf(float x) {
    float e = __expf(fminf(x, 15.0f));
    float n = e * (e + 2.0f);
    return x * n * __builtin_amdgcn_rcpf(n + 2.0f);
}
// truncating hi/lo split (3 VALU ops, reconstruction err ~2^-16)
__device__ __forceinline__ void splitv(float v, u16& h, u16& l) {
    u32 u = __builtin_bit_cast(u32, v);
    h = (u16)(u >> 16);
    float r = v - __builtin_bit_cast(float, u & 0xffff0000u);
    l = (u16)(__builtin_bit_cast(u32, r) >> 16);
}

__device__ __forceinline__ void zero2(f32x4* acc) {
    f32x4 z4 = {0.f, 0.f, 0.f, 0.f};
    acc[0] = z4; acc[1] = z4;
}

// prefetch the kb=0 B fragments (bh/bl for j=0,1) of a weight matrix into
// registers — issued BEFORE a __syncthreads so the L2 latency is absorbed
// in the barrier drain instead of serializing after it. 16 VGPR.
// DEPTH=1 IS THE OPTIMUM [measured r5/r7/r8]. Do not deepen again.
__device__ __forceinline__ void prefetchB4(const u16* __restrict__ Wh, const u16* __restrict__ Wl,
                                           int lane, int ntB, bf16x8* pre)
{
    size_t b0 = (((size_t)ntB + 0) * 64 + lane) * 8;   // kb=0
    size_t b1 = (((size_t)ntB + 1) * 64 + lane) * 8;
    pre[0] = *(const bf16x8*)(Wh + b0);
    pre[1] = *(const bf16x8*)(Wl + b0);
    pre[2] = *(const bf16x8*)(Wh + b1);
    pre[3] = *(const bf16x8*)(Wl + b1);
}

// 2-nt-tile GEMM slice. NM=1: ah*bh ; NM=2: ah*(bh+bl) ; NM=3: + al*bh
template<int NM>
__device__ __forceinline__ void gemm2(const bf16x8* ah, const bf16x8* al,
    const u16* __restrict__ Wh, const u16* __restrict__ Wl, int lane, int ntB, f32x4* acc)
{
#pragma unroll
    for (int kb = 0; kb < 4; kb++)
#pragma unroll
        for (int j = 0; j < 2; j++) {
            size_t boff = (((size_t)kb * 8 + ntB + j) * 64 + lane) * 8;
            bf16x8 bh = *(const bf16x8*)(Wh + boff);
            acc[j] = __builtin_amdgcn_mfma_f32_16x16x32_bf16(ah[kb], bh, acc[j], 0, 0, 0);
            if (NM >= 2) {
                bf16x8 bl = *(const bf16x8*)(Wl + boff);
                acc[j] = __builtin_amdgcn_mfma_f32_16x16x32_bf16(ah[kb], bl, acc[j], 0, 0, 0);
            }
            if (NM == 3)
                acc[j] = __builtin_amdgcn_mfma_f32_16x16x32_bf16(al[kb], bh, acc[j], 0, 0, 0);
        }
}

// dual NM=1 pair, SHARED A (fronthist As+Bs; round-10, measured neutral, kept)
__device__ __forceinline__ void gemm2_dual1(const bf16x8* ah,
    const u16* __restrict__ W1h, const u16* __restrict__ W2h,
    int lane, int ntB, f32x4* acc1, f32x4* acc2)
{
#pragma unroll
    for (int kb = 0; kb < 4; kb++)
#pragma unroll
        for (int j = 0; j < 2; j++) {
            size_t boff = (((size_t)kb * 8 + ntB + j) * 64 + lane) * 8;
            bf16x8 b1 = *(const bf16x8*)(W1h + boff);
            acc1[j] = __builtin_amdgcn_mfma_f32_16x16x32_bf16(ah[kb], b1, acc1[j], 0, 0, 0);
            bf16x8 b2 = *(const bf16x8*)(W2h + boff);
            acc2[j] = __builtin_amdgcn_mfma_f32_16x16x32_bf16(ah[kb], b2, acc2[j], 0, 0, 0);
        }
}

// dual NM=3 pair, SHARED A (fronthist At+Bt; round-10, measured neutral, kept)
__device__ __forceinline__ void gemm2_dual3(const bf16x8* ah, const bf16x8* al,
    const u16* __restrict__ W1h, const u16* __restrict__ W1l,
    const u16* __restrict__ W2h, const u16* __restrict__ W2l,
    int lane, int ntB, f32x4* acc1, f32x4* acc2)
{
#pragma unroll
    for (int kb = 0; kb < 4; kb++)
#pragma unroll
        for (int j = 0; j < 2; j++) {
            size_t boff = (((size_t)kb * 8 + ntB + j) * 64 + lane) * 8;
            bf16x8 b1h = *(const bf16x8*)(W1h + boff);
            bf16x8 b1l = *(const bf16x8*)(W1l + boff);
            acc1[j] = __builtin_amdgcn_mfma_f32_16x16x32_bf16(ah[kb], b1h, acc1[j], 0, 0, 0);
            acc1[j] = __builtin_amdgcn_mfma_f32_16x16x32_bf16(ah[kb], b1l, acc1[j], 0, 0, 0);
            acc1[j] = __builtin_amdgcn_mfma_f32_16x16x32_bf16(al[kb], b1h, acc1[j], 0, 0, 0);
            bf16x8 b2h = *(const bf16x8*)(W2h + boff);
            bf16x8 b2l = *(const bf16x8*)(W2l + boff);
            acc2[j] = __builtin_amdgcn_mfma_f32_16x16x32_bf16(ah[kb], b2h, acc2[j], 0, 0, 0);
            acc2[j] = __builtin_amdgcn_mfma_f32_16x16x32_bf16(ah[kb], b2l, acc2[j], 0, 0, 0);
            acc2[j] = __builtin_amdgcn_mfma_f32_16x16x32_bf16(al[kb], b2h, acc2[j], 0, 0, 0);
        }
}

// gemm2 with kb=0 B fragments preloaded (pre[0..3] = bh0,bl0,bh1,bl1)
template<int NM>
__device__ __forceinline__ void gemm2_pre(const bf16x8* ah, const bf16x8* al,
    const u16* __restrict__ Wh, const u16* __restrict__ Wl, int lane, int ntB,
    f32x4* acc, const bf16x8* pre)
{
#pragma unroll
    for (int kb = 0; kb < 4; kb++)
#pragma unroll
        for (int j = 0; j < 2; j++) {
            size_t boff = (((size_t)kb * 8 + ntB + j) * 64 + lane) * 8;
            bf16x8 bh = (kb == 0) ? pre[j * 2] : *(const bf16x8*)(Wh + boff);
            acc[j] = __builtin_amdgcn_mfma_f32_16x16x32_bf16(ah[kb], bh, acc[j], 0, 0, 0);
            if (NM >= 2) {
                bf16x8 bl = (kb == 0) ? pre[j * 2 + 1] : *(const bf16x8*)(Wl + boff);
                acc[j] = __builtin_amdgcn_mfma_f32_16x16x32_bf16(ah[kb], bl, acc[j], 0, 0, 0);
            }
            if (NM == 3)
                acc[j] = __builtin_amdgcn_mfma_f32_16x16x32_bf16(al[kb], bh, acc[j], 0, 0, 0);
        }
}

// dual-A NM=2 GEMM pair; stream-1 kb=0 fragments preloaded via pre.
// (shared-B case W2==W1 reuses b1h/b1l registers.)
__device__ __forceinline__ void gemm2_dual_pre(const bf16x8* a1, const bf16x8* a2,
    const u16* __restrict__ W1h, const u16* __restrict__ W1l,
    const u16* __restrict__ W2h, const u16* __restrict__ W2l,
    int lane, int ntB, f32x4* acc1, f32x4* acc2, const bf16x8* pre)
{
#pragma unroll
    for (int kb = 0; kb < 4; kb++)
#pragma unroll
        for (int j = 0; j < 2; j++) {
            size_t boff = (((size_t)kb * 8 + ntB + j) * 64 + lane) * 8;
            bf16x8 b1h = (kb == 0) ? pre[j * 2]     : *(const bf16x8*)(W1h + boff);
            bf16x8 b1l = (kb == 0) ? pre[j * 2 + 1] : *(const bf16x8*)(W1l + boff);
            acc1[j] = __builtin_amdgcn_mfma_f32_16x16x32_bf16(a1[kb], b1h, acc1[j], 0, 0, 0);
            acc1[j] = __builtin_amdgcn_mfma_f32_16x16x32_bf16(a1[kb], b1l, acc1[j], 0, 0, 0);
            bf16x8 b2h = (W2h == W1h) ? b1h : *(const bf16x8*)(W2h + boff);
            bf16x8 b2l = (W2l == W1l) ? b1l : *(const bf16x8*)(W2l + boff);
            acc2[j] = __builtin_amdgcn_mfma_f32_16x16x32_bf16(a2[kb], b2h, acc2[j], 0, 0, 0);
            acc2[j] = __builtin_amdgcn_mfma_f32_16x16x32_bf16(a2[kb], b2l, acc2[j], 0, 0, 0);
        }
}

__device__ __forceinline__ void frag_hi_global16(const u16* __restrict__ src, int row0,
                                                 int lm, int quad, int M, bf16x8* ah)
{
    int row = row0 + lm; if (row >= M) row = M - 1;
    const u16* p = src + (size_t)row * DD + quad * 8;
#pragma unroll
    for (int kb = 0; kb < 4; kb++) ah[kb] = *(const bf16x8*)(p + kb * 32);
}
__device__ __forceinline__ void frag_split_global16(const float* __restrict__ src, int row0,
                                                    int lm, int quad, int M, bf16x8* ah, bf16x8* al)
{
    int row = row0 + lm; if (row >= M) row = M - 1;
    const float* p = src + (size_t)row * DD + quad * 8;
#pragma unroll
    for (int kb = 0; kb < 4; kb++) {
        float tmp[8];
        *(float4*)tmp       = *(const float4*)(p + kb * 32);
        *(float4*)(tmp + 4) = *(const float4*)(p + kb * 32 + 4);
#pragma unroll
        for (int j = 0; j < 8; j++) { u16 h, l; splitv(tmp[j], h, l); ah[kb][j] = (short)h; al[kb][j] = (short)l; }
    }
}
__device__ __forceinline__ void frag_hi_plane16(const u16* P, int lm, int quad, bf16x8* ah)
{
    const u16* p = P + (size_t)lm * LDSS + quad * 8;
#pragma unroll
    for (int kb = 0; kb < 4; kb++) ah[kb] = *(const bf16x8*)(p + kb * 32);
}
__device__ __forceinline__ void frag_planes16(const u16* PH, const u16* PL, int lm, int quad,
                                              bf16x8* ah, bf16x8* al)
{
    const u16* ph = PH + (size_t)lm * LDSS + quad * 8;
    const u16* pl = PL + (size_t)lm * LDSS + quad * 8;
#pragma unroll
    for (int kb = 0; kb < 4; kb++) {
        ah[kb] = *(const bf16x8*)(ph + kb * 32);
        al[kb] = *(const bf16x8*)(pl + kb * 32);
    }
}

// ============ weight prep ============
struct WSrc { const float* p[18]; };

__global__ __launch_bounds__(256) void prep_weights(WSrc ws, u16* __restrict__ Wh, u16* __restrict__ Wl)
{
    int mat = blockIdx.x >> 3, chunk = blockIdx.x & 7;
    int t = threadIdx.x;
    int tt = chunk * 4 + (t >> 6);
    int lane = t & 63;
    int kb = tt >> 3, nt = tt & 7;
    const float* __restrict__ src = ws.p[mat];
    size_t doff = (size_t)mat * WT + ((size_t)tt * 64 + lane) * 8;
    int srow = kb * 32 + ((lane >> 4) * 8);
    int scol = nt * 16 + (lane & 15);
    u16 th[8], tl[8];
#pragma unroll
    for (int j = 0; j < 8; j++) {
        float v = src[(srow + j) * DD + scol];
        u16 h = f2bf(v);
        th[j] = h;
        tl[j] = f2bf(v - bf2f(h));
    }
    *(bf16x8*)(Wh + doff) = *(bf16x8*)th;
    *(bf16x8*)(Wl + doff) = *(bf16x8*)tl;
}

// ============ front + hist packed in one launch ============
// G layout: per-lane-interleaved — row = 64 lanes x 12B triplets {As, Bs, xb}
// (u32 each); edge_agg reads one dwordx3 per edge. [round 7 win]
// Round-10 dualization (As+Bs, At+Bt): measured neutral, kept.
__global__ __launch_bounds__(256, 4) void fronthist_kernel(
    const float* __restrict__ x, const u16* __restrict__ Wh, const u16* __restrict__ Wl,
    u16* __restrict__ G, u16* __restrict__ xWs,
    float* __restrict__ At, float* __restrict__ Bt, float* __restrict__ Ct,
    const int* __restrict__ ei, int* __restrict__ deg, int E, int M, int NBF)
{
    __shared__ u16 sP[3 * PLANE];
    const int t = threadIdx.x;
    if ((int)blockIdx.x >= NBF) {           // ---- histogram part ----
        int e = ((int)blockIdx.x - NBF) * 256 + t;
        if (e < E) atomicAdd(&deg[ei[E + e]], 1);
        return;
    }
    u16 *P0 = sP, *P1 = sP + PLANE, *P2 = sP + 2 * PLANE;
    const int wave = t >> 6, lane = t & 63;
    const int lm = lane & 15, quad = lane >> 4;
    const int ntB = wave * 2;
    const int row0 = blockIdx.x * 16;

    bf16x8 ah[4], al[4];
    {   // every wave loads the same 16 rows (L1 hits); wave 0 writes the xb plane
        int row = row0 + lm; if (row >= M) row = M - 1;
        const float* p = x + (size_t)row * DD + quad * 8;
#pragma unroll
        for (int kb = 0; kb < 4; kb++) {
            float tmp[8];
            *(float4*)tmp       = *(const float4*)(p + kb * 32);
            *(float4*)(tmp + 4) = *(const float4*)(p + kb * 32 + 4);
#pragma unroll
            for (int j = 0; j < 8; j++) {
                u16 h, l; splitv(tmp[j], h, l);
                ah[kb][j] = (short)h; al[kb][j] = (short)l;
                if (wave == 0) P0[lm * LDSS + kb * 32 + quad * 8 + j] = f2bf(tmp[j]);
            }
        }
    }
    {   // As = x@W1 -> P1  ||  Bs = x@W3 -> P2  (dual NM=1, shared A)
        f32x4 accA[2], accB[2]; zero2(accA); zero2(accB);
        gemm2_dual1(ah, Wh + 1 * WT, Wh + 3 * WT, lane, ntB, accA, accB);
#pragma unroll
        for (int r = 0; r < 4; r++)
#pragma unroll
            for (int j = 0; j < 2; j++) {
                int lidx = (quad * 4 + r) * LDSS + (ntB + j) * 16 + lm;
                P1[lidx] = f2bf(accA[j][r]);
                P2[lidx] = f2bf(accB[j][r]);
            }
    }
    __syncthreads();   // single barrier: planes complete, drain all three
#pragma unroll
    for (int i = 0; i < 4; i++) {
        int r = wave * 4 + i;
        int grow = row0 + r;
        if (grow >= M) continue;
        u16* gp = G + (size_t)grow * 384 + lane * 6;
        u32x3 v;
        v.x = *(const u32*)&P1[r * LDSS + lane * 2];   // As
        v.y = *(const u32*)&P2[r * LDSS + lane * 2];   // Bs
        v.z = *(const u32*)&P0[r * LDSS + lane * 2];   // xb
        *(u32x3*)gp = v;                               // dwordx3, 768B/wave contiguous
    }
    {   // xWs = x@W5 -> global bf16
        f32x4 acc[2]; zero2(acc);
        gemm2<1>(ah, ah, Wh + 5 * WT, Wh, lane, ntB, acc);
#pragma unroll
        for (int r = 0; r < 4; r++) {
            int grow = row0 + quad * 4 + r;
            if (grow >= M) continue;
#pragma unroll
            for (int j = 0; j < 2; j++)
                xWs[(size_t)grow * DD + (ntB + j) * 16 + lm] = f2bf(acc[j][r]);
        }
    }
    {   // At = split-x@W0  ||  Bt = split-x@W2  (dual NM=3, shared A)
        f32x4 accA[2], accB[2]; zero2(accA); zero2(accB);
        gemm2_dual3(ah, al, Wh + 0 * WT, Wl + 0 * WT, Wh + 2 * WT, Wl + 2 * WT,
                    lane, ntB, accA, accB);
#pragma unroll
        for (int r = 0; r < 4; r++) {
            int grow = row0 + quad * 4 + r;
            if (grow >= M) continue;
#pragma unroll
            for (int j = 0; j < 2; j++) {
                At[(size_t)grow * DD + (ntB + j) * 16 + lm] = accA[j][r];
                Bt[(size_t)grow * DD + (ntB + j) * 16 + lm] = accB[j][r];
            }
        }
    }
    {   // Ct = split-x@W4 (single NM=3)
        f32x4 acc[2]; zero2(acc);
        gemm2<3>(ah, al, Wh + 4 * WT, Wl + 4 * WT, lane, ntB, acc);
#pragma unroll
        for (int r = 0; r < 4; r++) {
            int grow = row0 + quad * 4 + r;
            if (grow >= M) continue;
#pragma unroll
            for (int j = 0; j < 2; j++)
                Ct[(size_t)grow * DD + (ntB + j) * 16 + lm] = acc[j][r];
        }
    }
}

// ============ CSR scan (3-phase parallel) ============
// [round 9: replaced 1-block serial scan — total 603->509us, -94us]
__global__ __launch_bounds__(256) void scan_partial(const int* __restrict__ deg,
                                                    int* __restrict__ bsum, int N)
{
    int t = threadIdx.x;
    int base = blockIdx.x * SCAN_TILE + t * 4;
    int s = 0;
    if (base + 3 < N) {
        int4 v = *(const int4*)(deg + base);
        s = v.x + v.y + v.z + v.w;
    } else {
        for (int i = 0; i < 4; i++) if (base + i < N) s += deg[base + i];
    }
    __shared__ int red[256];
    red[t] = s;
    __syncthreads();
    for (int off = 128; off > 0; off >>= 1) {
        if (t < off) red[t] += red[t + off];
        __syncthreads();
    }
    if (t == 0) bsum[blockIdx.x] = red[0];
}

__global__ __launch_bounds__(64) void scan_mid(const int* __restrict__ bsum,
                                               int* __restrict__ boff,
                                               int* __restrict__ rowptr, int nblk, int N)
{
    int l = threadIdx.x;
    int mine = (l < nblk) ? bsum[l] : 0;
    int v = mine;
    for (int off = 1; off < 64; off <<= 1) {       // inclusive wave scan (nblk <= 64)
        int u = __shfl_up(v, off);
        if (l >= off) v += u;
    }
    if (l < nblk) boff[l] = v - mine;              // exclusive
    if (l == 63) rowptr[N] = v;                    // grand total = E
}

__global__ __launch_bounds__(256) void scan_fill(const int* __restrict__ deg,
                                                 const int* __restrict__ boff,
                                                 int* __restrict__ rowptr,
                                                 int* __restrict__ cursor, int N)
{
    int t = threadIdx.x;
    int base = blockIdx.x * SCAN_TILE + t * 4;
    int d[4] = {0, 0, 0, 0};
    if (base + 3 < N) {
        int4 v = *(const int4*)(deg + base);
        d[0] = v.x; d[1] = v.y; d[2] = v.z; d[3] = v.w;
    } else {
        for (int i = 0; i < 4; i++) if (base + i < N) d[i] = deg[base + i];
    }
    int s = d[0] + d[1] + d[2] + d[3];
    __shared__ int pf[256];
    pf[t] = s;
    __syncthreads();
    for (int off = 1; off < 256; off <<= 1) {      // Hillis-Steele inclusive
        int v = pf[t];
        int u = (t >= off) ? pf[t - off] : 0;
        __syncthreads();
        pf[t] = v + u;
        __syncthreads();
    }
    int run = boff[blockIdx.x] + pf[t] - s;        // exclusive prefix for this thread
    for (int i = 0; i < 4; i++) {
        int idx = base + i;
        if (idx < N) {
            rowptr[idx] = run;
            cursor[idx] = run;
            run += d[i];
        }
    }
}

__global__ __launch_bounds__(256) void scatter_kernel(
    const int* __restrict__ ei, const int* __restrict__ bond,
    const float* __restrict__ coords, int* __restrict__ cursor,
    int2* __restrict__ csr, int E)
{
    int e = blockIdx.x * 256 + threadIdx.x;
    if (e >= E) return;
    int src = ei[e], dst = ei[E + e];
    int pos = atomicAdd(&cursor[dst], 1);
    float dx = coords[src * 3 + 0] - coords[dst * 3 + 0];
    float dy = coords[src * 3 + 1] - coords[dst * 3 + 1];
    float dz = coords[src * 3 + 2] - coords[dst * 3 + 2];
    float d2 = dx * dx + dy * dy + dz * dz;
    csr[pos] = make_int2(src | (bond[e] << 20), __float_as_int(d2));
}

// ============ per-node edge aggregation ============
// 1 wave/node; interleaved-G dwordx3 gathers + 8-edge pipeline [round 7 win].
// Near its L3-BW floor (~614MB of fully-consumed G-row gathers).
__global__ __launch_bounds__(256) void edge_agg(
    const float* __restrict__ At, const float* __restrict__ Bt,
    const u16* __restrict__ G,
    const int* __restrict__ rowptr, const int2* __restrict__ csr,
    const float* __restrict__ conv_w, const float* __restrict__ conv_b,
    const float* __restrict__ b_nb, const float* __restrict__ b_el,
    u16* __restrict__ Pn, u16* __restrict__ Pe, float* __restrict__ z,
    float* __restrict__ s_arr, int N)
{
    int wave = threadIdx.x >> 6;
    int lane = threadIdx.x & 63;
    int node = blockIdx.x * 4 + wave;
    if (node >= N) return;
    int c0 = lane * 2;
    int lane6 = lane * 6;
    float2 at = *(const float2*)(At + (size_t)node * DD + c0);
    float2 bt = *(const float2*)(Bt + (size_t)node * DD + c0);
    float cb = conv_b[0];
    float cw0 = conv_w[0] + cb, cw1 = conv_w[1] + cb, cw2 = conv_w[2] + cb, cw3 = conv_w[3] + cb;
    float bn0 = b_nb[c0], bn1 = b_nb[c0 + 1];
    float be0 = b_el[c0], be1 = b_el[c0 + 1];
    float accn0 = 0.f, accn1 = 0.f, acce0 = 0.f, acce1 = 0.f, accz0 = 0.f, accz1 = 0.f, ssum = 0.f;
    int beg = rowptr[node], end = rowptr[node + 1];

    auto consume = [&](int px, float d2, u32 ga, u32 gb, u32 gx) {
        int bondv = (px >> 20) & 3;
        float w = (bondv == 0) ? cw0 : (bondv == 1) ? cw1 : (bondv == 2) ? cw2 : cw3;
        float a0 = __builtin_bit_cast(float, ga << 16), a1 = __builtin_bit_cast(float, ga & 0xffff0000u);
        float b0 = __builtin_bit_cast(float, gb << 16), b1 = __builtin_bit_cast(float, gb & 0xffff0000u);
        float x0 = __builtin_bit_cast(float, gx << 16), x1 = __builtin_bit_cast(float, gx & 0xffff0000u);
        accn0 += mishf(at.x + a0 + bn0);
        accn1 += mishf(at.y + a1 + bn1);
        acce0 += mishf(w * (bt.x + b0) + be0);
        acce1 += mishf(w * (bt.y + b1) + be1);
        accz0 += d2 * x0;
        accz1 += d2 * x1;
        ssum += d2;
    };

    int k = beg;
    for (; k + 8 <= end; k += 8) {      // 8 edges in flight, 1 dwordx3 each
        int2 pd[8];
        u32x3 g[8];
#pragma unroll
        for (int i = 0; i < 8; i++) pd[i] = csr[k + i];
#pragma unroll
        for (int i = 0; i < 8; i++)
            g[i] = *(const u32x3*)(G + (size_t)(pd[i].x & 0xFFFFF) * 384 + lane6);
#pragma unroll
        for (int i = 0; i < 8; i++)
            consume(pd[i].x, __int_as_float(pd[i].y), g[i].x, g[i].y, g[i].z);
    }
    for (; k + 4 <= end; k += 4) {
        int2 pd[4];
        u32x3 g[4];
#pragma unroll
        for (int i = 0; i < 4; i++) pd[i] = csr[k + i];
#pragma unroll
        for (int i = 0; i < 4; i++)
            g[i] = *(const u32x3*)(G + (size_t)(pd[i].x & 0xFFFFF) * 384 + lane6);
#pragma unroll
        for (int i = 0; i < 4; i++)
            consume(pd[i].x, __int_as_float(pd[i].y), g[i].x, g[i].y, g[i].z);
    }
    for (; k < end; k++) {
        int2 pd = csr[k];
        u32x3 g = *(const u32x3*)(G + (size_t)(pd.x & 0xFFFFF) * 384 + lane6);
        consume(pd.x, __int_as_float(pd.y), g.x, g.y, g.z);
    }

    *(u32*)(Pn + (size_t)node * DD + c0) = (u32)f2bf(accn0) | ((u32)f2bf(accn1) << 16);
    *(u32*)(Pe + (size_t)node * DD + c0) = (u32)f2bf(acce0) | ((u32)f2bf(acce1) << 16);
    *(float2*)(z + (size_t)node * DD + c0) = make_float2(accz0, accz1);
    if (lane == 0) s_arr[node] = ssum;
}

// ============ mega v5: phase-merged, 4 waves/SIMD, cross-phase reg relief ====
// ROUND 13: r12's (256,4) cap left a 1-reg scratch spill (WRITE 28125->31250).
// Relief of 16 cross-barrier VGPRs, zero arithmetic change:
//  - f1p/f2p registers DROPPED: phase E re-reads f_n/f_e from PA/PB (written
//    in phase A; each thread reads its OWN slots right before overwriting
//    with att — thread-disjoint addresses, no race, bit-identical values).
//  - d1v spilled to dead LDS (PC/PD planes unused between phase C and the
//    final reduction); layout [i*256+t] = stride-1 across lanes, conflict-free.
// Spill tripwire: WRITE_SIZE must return to exactly 28125 KB.
__global__ __launch_bounds__(256, 4) void mega_kernel(
    const u16* __restrict__ Pn, const u16* __restrict__ Pe, const float* __restrict__ z,
    const float* __restrict__ Ct, const u16* __restrict__ xWs,
    const float* __restrict__ s_arr, const int* __restrict__ deg,
    const float* __restrict__ b_nout, const float* __restrict__ b_eout,
    const float* __restrict__ b_coord, const float* __restrict__ b_pair,
    const float* __restrict__ b_sout,
    const u16* __restrict__ Wh, const u16* __restrict__ Wl,
    float* __restrict__ hout, float* __restrict__ bnsums, int M)
{
    __shared__ u16 sP[8 * PLANE];
    u16 *PA = sP,             *PB = sP + PLANE,     *PC = sP + 2 * PLANE, *PD = sP + 3 * PLANE;
    u16 *PE = sP + 4 * PLANE, *PF = sP + 5 * PLANE, *PG = sP + 6 * PLANE, *PH = sP + 7 * PLANE;
    float* dspill = (float*)(sP + 2 * PLANE);      // 8KB in PC/PD, dead C->end
    const int t = threadIdx.x, wave = t >> 6, lane = t & 63;
    const int lm = lane & 15, quad = lane >> 4;
    const int ntB = wave * 2;
    const int row0 = blockIdx.x * 16;

    u32 f3p[4];
    float d2v[8];
    bf16x8 preB[4];

    // ======== Phase A: n/e stage1 + struct S1 ========
    prefetchB4(Wh + 11 * WT, Wl + 11 * WT, lane, ntB, preB);
    {
        bf16x8 an[4], ae[4];
        f32x4 accn[2], acce[2];
        frag_hi_global16(Pn, row0, lm, quad, M, an);
        frag_hi_global16(Pe, row0, lm, quad, M, ae);
        zero2(accn); zero2(acce);
        gemm2_dual_pre(an, ae, Wh + 11 * WT, Wl + 11 * WT, Wh + 12 * WT, Wl + 12 * WT, lane, ntB, accn, acce, preB);
#pragma unroll
        for (int r = 0; r < 4; r++)
#pragma unroll
            for (int j = 0; j < 2; j++) {
                int col = (ntB + j) * 16 + lm;
                int lidx = (quad * 4 + r) * LDSS + col;
                PA[lidx] = f2bf(mishf(accn[j][r] + b_nout[col]));
                PB[lidx] = f2bf(mishf(acce[j][r] + b_eout[col]));
            }
    }
    {   // struct S1: Qagg = z@W8 + s*Ct + deg*b_coord -> PE/PF
        bf16x8 ah[4], al[4];
        f32x4 acc[2];
        frag_split_global16(z, row0, lm, quad, M, ah, al);
        zero2(acc);
        gemm2<3>(ah, al, Wh + 8 * WT, Wl + 8 * WT, lane, ntB, acc);
#pragma unroll
        for (int r = 0; r < 4; r++) {
            int crow = row0 + quad * 4 + r; if (crow >= M) crow = M - 1;
            float sv = s_arr[crow];
            float dv = (float)deg[crow];
#pragma unroll
            for (int j = 0; j < 2; j++) {
                int col = (ntB + j) * 16 + lm;
                float v = acc[j][r] + sv * Ct[(size_t)crow * DD + col] + dv * b_coord[col];
                int lidx = (quad * 4 + r) * LDSS + col;
                u16 h, l; splitv(v, h, l); PE[lidx] = h; PF[lidx] = l;
            }
        }
    }
    prefetchB4(Wh + 13 * WT, Wl + 13 * WT, lane, ntB, preB);
    __syncthreads();

    // ======== Phase B: n/e stage2 + struct S2 ========
    {
        bf16x8 an[4], ae[4];
        f32x4 accn[2], acce[2];
        frag_hi_plane16(PA, lm, quad, an);
        frag_hi_plane16(PB, lm, quad, ae);
        zero2(accn); zero2(acce);
        gemm2_dual_pre(an, ae, Wh + 13 * WT, Wl + 13 * WT, Wh + 14 * WT, Wl + 14 * WT, lane, ntB, accn, acce, preB);
#pragma unroll
        for (int r = 0; r < 4; r++)
#pragma unroll
            for (int j = 0; j < 2; j++) {
                int lidx = (quad * 4 + r) * LDSS + (ntB + j) * 16 + lm;
                PC[lidx] = f2bf(mishf(mishf(accn[j][r])));
                PD[lidx] = f2bf(mishf(mishf(acce[j][r])));
            }
    }
    {   // struct S2: Q = mish(Qagg@W9 + b_pair) -> PG/PH
        bf16x8 ah[4], al[4];
        f32x4 acc[2];
        frag_planes16(PE, PF, lm, quad, ah, al);
        zero2(acc);
        gemm2<3>(ah, al, Wh + 9 * WT, Wl + 9 * WT, lane, ntB, acc);
#pragma unroll
        for (int r = 0; r < 4; r++)
#pragma unroll
            for (int j = 0; j < 2; j++) {
                int col = (ntB + j) * 16 + lm;
                int lidx = (quad * 4 + r) * LDSS + col;
                u16 h, l; splitv(mishf(acc[j][r] + b_pair[col]), h, l); PG[lidx] = h; PH[lidx] = l;
            }
    }
    prefetchB4(Wh + 16 * WT, Wl + 16 * WT, lane, ntB, preB);
    __syncthreads();

    // ======== Phase C: n/e stage3 (shared W16) + struct S3 ========
    {
        bf16x8 an[4], ae[4];
        f32x4 accn[2], acce[2];
        frag_hi_plane16(PC, lm, quad, an);
        frag_hi_plane16(PD, lm, quad, ae);
        zero2(accn); zero2(acce);
        gemm2_dual_pre(an, ae, Wh + 16 * WT, Wl + 16 * WT, Wh + 16 * WT, Wl + 16 * WT, lane, ntB, accn, acce, preB);
        // d1 -> LDS spill (PC/PD dead after the frag reads above within this
        // phase; all waves pass the same point before the C->D barrier, and
        // dspill slots are thread-private). d2 stays in registers.
#pragma unroll
        for (int r = 0; r < 4; r++)
#pragma unroll
            for (int j = 0; j < 2; j++) {
                d2v[r * 2 + j] = acce[j][r];
            }
        __syncthreads();   // ensure ALL waves finished reading PC/PD as frags
#pragma unroll
        for (int r = 0; r < 4; r++)
#pragma unroll
            for (int j = 0; j < 2; j++)
                dspill[(r * 2 + j) * 256 + t] = accn[j][r];
    }
    {   // struct S3: f_struct = mish(Q@W10 + xWs + b_sout) -> f3 regs + PE/PF
        bf16x8 ah[4], al[4];
        f32x4 acc[2];
        frag_planes16(PG, PH, lm, quad, ah, al);
        zero2(acc);
        gemm2<3>(ah, al, Wh + 10 * WT, Wl + 10 * WT, lane, ntB, acc);
#pragma unroll
        for (int r = 0; r < 4; r++) {
            int crow = row0 + quad * 4 + r; if (crow >= M) crow = M - 1;
            u32 pk = 0;
#pragma unroll
            for (int j = 0; j < 2; j++) {
                int col = (ntB + j) * 16 + lm;
                float v = mishf(acc[j][r] + bf2f(xWs[(size_t)crow * DD + col]) + b_sout[col]);
                u16 h, l; splitv(v, h, l);
                pk |= ((u32)f2bf(v)) << (16 * j);
                int lidx = (quad * 4 + r) * LDSS + col;
                PE[lidx] = h; PF[lidx] = l;
            }
            f3p[r] = pk;
        }
    }
    prefetchB4(Wh + 15 * WT, Wl + 15 * WT, lane, ntB, preB);
    __syncthreads();

    // ======== Phase D: struct S4 ========
    bf16x8 ah[4], al[4];
    f32x4 acc[2];
    frag_planes16(PE, PF, lm, quad, ah, al);
    zero2(acc);
    gemm2_pre<3>(ah, al, Wh + 15 * WT, Wl + 15 * WT, lane, ntB, acc, preB);
#pragma unroll
    for (int r = 0; r < 4; r++)
#pragma unroll
        for (int j = 0; j < 2; j++) {
            int lidx = (quad * 4 + r) * LDSS + (ntB + j) * 16 + lm;
            u16 h, l; splitv(mishf(mishf(acc[j][r])), h, l); PG[lidx] = h; PH[lidx] = l;
        }
    prefetchB4(Wh + 16 * WT, Wl + 16 * WT, lane, ntB, preB);
    __syncthreads();

    // ======== Phase E: struct S5 + softmax -> att -> PA/PB ========
    frag_planes16(PG, PH, lm, quad, ah, al);
    zero2(acc);
    gemm2_pre<3>(ah, al, Wh + 16 * WT, Wl + 16 * WT, lane, ntB, acc, preB);
#pragma unroll
    for (int r = 0; r < 4; r++)
#pragma unroll
        for (int j = 0; j < 2; j++) {
            int i = r * 2 + j;
            int lidx = (quad * 4 + r) * LDSS + (ntB + j) * 16 + lm;
            float x1 = dspill[i * 256 + t], x2 = d2v[i], x3 = acc[j][r];
            float m = fmaxf(fmaxf(x1, x2), x3);
            float p1 = __expf(x1 - m), p2 = __expf(x2 - m), p3 = __expf(x3 - m);
            float fv1 = bf2f(PA[lidx]);               // own slot, written in phase A
            float fv2 = bf2f(PB[lidx]);
            float fv3 = bf2f((u16)(f3p[r] >> (16 * j)));
            float att = (p1 * fv1 + p2 * fv2 + p3 * fv3) * __builtin_amdgcn_rcpf(p1 + p2 + p3);
            u16 h, l; splitv(att, h, l); PA[lidx] = h; PB[lidx] = l;   // overwrite own slot
        }
    prefetchB4(Wh + 17 * WT, Wl + 17 * WT, lane, ntB, preB);
    __syncthreads();

    // ======== Phase F: h_agg = att@W17 -> hout + BN partial sums ========
    frag_planes16(PA, PB, lm, quad, ah, al);
    zero2(acc);
    gemm2_pre<3>(ah, al, Wh + 17 * WT, Wl + 17 * WT, lane, ntB, acc, preB);
    float s[2] = {0.f, 0.f}, q[2] = {0.f, 0.f};
#pragma unroll
    for (int r = 0; r < 4; r++) {
        int grow = row0 + quad * 4 + r;
        if (grow >= M) continue;
#pragma unroll
        for (int j = 0; j < 2; j++) {
            float v = acc[j][r];
            hout[(size_t)grow * DD + (ntB + j) * 16 + lm] = v;
            s[j] += v; q[j] += v * v;
        }
    }
    // per-block column reduction in LDS (planes dead), then global atomics
    __syncthreads();
    float* red = (float*)sP;                 // 256 floats (PA region; dspill untouched)
    if (t < 128) { red[t] = 0.f; red[128 + t] = 0.f; }
    __syncthreads();
#pragma unroll
    for (int j = 0; j < 2; j++) {
        int col = (ntB + j) * 16 + lm;
        atomicAdd(&red[col], s[j]);
        atomicAdd(&red[128 + col], q[j]);
    }
    __syncthreads();
    if (t < 128) {
        atomicAdd(&bnsums[t], red[t]);
        atomicAdd(&bnsums[128 + t], red[128 + t]);
    }
}

// ============ batchnorm finalize + apply ============
__global__ void bn_finalize(const float* __restrict__ sums, const float* __restrict__ gamma,
                            const float* __restrict__ beta, float* __restrict__ scale,
                            float* __restrict__ shift, float n_inv)
{
    int c = threadIdx.x;
    float mean = sums[c] * n_inv;
    float var = sums[128 + c] * n_inv - mean * mean;
    float inv = rsqrtf(var + 1e-5f);
    float sc = gamma[c] * inv;
    scale[c] = sc;
    shift[c] = beta[c] - mean * sc;
}

__global__ __launch_bounds__(256) void bn_apply(float* __restrict__ h, const float* __restrict__ scale,
                                                const float* __restrict__ shift, size_t total4)
{
    size_t idx = (size_t)blockIdx.x * 256 + threadIdx.x;
    if (idx >= total4) return;
    size_t off = idx * 4;
    int c = (int)(off & 127);
    float4 v = *(const float4*)(h + off);
    float4 sc = *(const float4*)(scale + c);
    float4 sh = *(const float4*)(shift + c);
    v.x = mishf(v.x * sc.x + sh.x);
    v.y = mishf(v.y * sc.y + sh.y);
    v.z = mishf(v.z * sc.z + sh.z);
    v.w = mishf(v.w * sc.w + sh.w);
    *(float4*)(h + off) = v;
}

// ============ host ============
extern "C" void kernel_launch(void* const* d_in, const int* in_sizes, int n_in,
                              void* d_out, int out_size, void* d_ws, size_t ws_size,
                              hipStream_t stream)
{
    (void)n_in; (void)out_size; (void)ws_size;
    const float* x       = (const float*)d_in[0];
    const float* coords  = (const float*)d_in[1];
    const int*   ei      = (const int*)d_in[2];
    const int*   bond    = (const int*)d_in[3];
    const float* W_nb    = (const float*)d_in[4];
    const float* b_nb    = (const float*)d_in[5];
    const float* W_nout  = (const float*)d_in[6];
    const float* b_nout  = (const float*)d_in[7];
    const float* conv_w  = (const float*)d_in[8];
    const float* conv_b  = (const float*)d_in[9];
    const float* W_el    = (const float*)d_in[10];
    const float* b_el    = (const float*)d_in[11];
    const float* W_eout  = (const float*)d_in[12];
    const float* b_eout  = (const float*)d_in[13];
    const float* W_coord = (const float*)d_in[14];
    const float* b_coord = (const float*)d_in[15];
    const float* W_pair  = (const float*)d_in[16];
    const float* b_pair  = (const float*)d_in[17];
    const float* W_sout  = (const float*)d_in[18];
    const float* b_sout  = (const float*)d_in[19];
    const float* W_init  = (const float*)d_in[20];
    const float* feat_lin= (const float*)d_in[21];
    const float* W_att   = (const float*)d_in[22];
    const float* W_agg   = (const float*)d_in[23];
    const float* gamma   = (const float*)d_in[24];
    const float* beta    = (const float*)d_in[25];

    const int N = in_sizes[0] / DD;     // 50000
    const int E = in_sizes[3];          // 800000
    const size_t ND = (size_t)N * DD;
    const int SUB = DD * DD;
    const int NB16 = (N + 15) / 16;
    const int EB   = (E + 255) / 256;
    const int NSCAN = (N + SCAN_TILE - 1) / SCAN_TILE;   // 49 blocks

    char* base = (char*)d_ws;
    size_t off = 0;
    auto alloc = [&](size_t bytes) -> char* {
        char* p = base + off;
        off = (off + bytes + 63) & ~(size_t)63;
        return p;
    };
    u16*   G    = (u16*)alloc((size_t)N * 384 * 2);
    u16*   xWs  = (u16*)alloc(ND * 2);
    float* At   = (float*)alloc(ND * 4);
    float* Bt   = (float*)alloc(ND * 4);
    float* Ct   = (float*)alloc(ND * 4);
    u16*   Pn   = (u16*)alloc(ND * 2);
    u16*   Pe   = (u16*)alloc(ND * 2);
    float* z    = (float*)alloc(ND * 4);
    u16*   Wh   = (u16*)alloc((size_t)18 * WT * 2);
    u16*   Wl   = (u16*)alloc((size_t)18 * WT * 2);
    int2*  csr  = (int2*)alloc((size_t)E * 8);
    int*   deg    = (int*)alloc((size_t)(N + 64) * 4);
    int*   rowptr = (int*)alloc((size_t)(N + 1) * 4);
    int*   cursor = (int*)alloc((size_t)N * 4);
    float* s_arr  = (float*)alloc((size_t)N * 4);
    int*   bsum   = (int*)alloc((size_t)(NSCAN + 64) * 4);
    int*   boff   = (int*)alloc((size_t)(NSCAN + 64) * 4);
    float* bnsums  = (float*)alloc(256 * 4);
    float* bnscale = (float*)alloc(128 * 4);
    float* bnshift = (float*)alloc(128 * 4);

    float* hout = (float*)d_out;

    WSrc wsrc;
    wsrc.p[0] = W_nb;            wsrc.p[1] = W_nb + SUB;
    wsrc.p[2] = W_el;            wsrc.p[3] = W_el + SUB;
    wsrc.p[4] = W_coord;         wsrc.p[5] = W_sout;
    wsrc.p[6] = W_init;          wsrc.p[7] = W_att;      // 6,7 unused (e0 cancels) — kept for layout
    wsrc.p[8] = W_coord + SUB;   wsrc.p[9] = W_pair;
    wsrc.p[10] = W_sout + SUB;   wsrc.p[11] = W_nout;
    wsrc.p[12] = W_eout;         wsrc.p[13] = feat_lin;
    wsrc.p[14] = feat_lin + SUB; wsrc.p[15] = feat_lin + 2 * SUB;
    wsrc.p[16] = W_att + SUB;    wsrc.p[17] = W_agg;

    const dim3 blk256(256);
    const size_t total4 = ND / 4;
    const dim3 gElem((unsigned)((total4 + 255) / 256));

    hipMemsetAsync(deg, 0, (size_t)N * 4, stream);
    hipMemsetAsync(bnsums, 0, 256 * 4, stream);

    prep_weights<<<dim3(18 * 8), blk256, 0, stream>>>(wsrc, Wh, Wl);
    fronthist_kernel<<<dim3(NB16 + EB), blk256, 0, stream>>>(x, Wh, Wl, G, xWs, At, Bt, Ct,
                                                             ei, deg, E, N, NB16);
    scan_partial<<<dim3(NSCAN), blk256, 0, stream>>>(deg, bsum, N);
    scan_mid<<<1, 64, 0, stream>>>(bsum, boff, rowptr, NSCAN, N);
    scan_fill<<<dim3(NSCAN), blk256, 0, stream>>>(deg, boff, rowptr, cursor, N);
    scatter_kernel<<<dim3(EB), blk256, 0, stream>>>(ei, bond, coords, cursor, csr, E);

    edge_agg<<<(N + 3) / 4, blk256, 0, stream>>>(At, Bt, G, rowptr, csr, conv_w, conv_b,
                                                 b_nb, b_el, Pn, Pe, z, s_arr, N);

    mega_kernel<<<NB16, blk256, 0, stream>>>(Pn, Pe, z, Ct, xWs, s_arr, deg,
                                             b_nout, b_eout, b_coord, b_pair, b_sout,
                                             Wh, Wl, hout, bnsums, N);

    bn_finalize<<<1, 128, 0, stream>>>(bnsums, gamma, beta, bnscale, bnshift, 1.0f / (float)N);
    bn_apply<<<gElem, blk256, 0, stream>>>(hout, bnscale, bnshift, total4);
}